// Round 1
// baseline (999.802 us; speedup 1.0000x reference)
//
#include <hip/hip_runtime.h>

#define NN 50000
#define NE 800000
#define HID 128
#define OUTC 64
#define NG 128
#define NLAY 3
#define BN_EPS 1e-5f

typedef __attribute__((ext_vector_type(8))) short bfrag;
typedef __attribute__((ext_vector_type(4))) float f4;

__device__ __forceinline__ ushort f2b(float f) {
    union { float f; unsigned u; } x; x.f = f;
    unsigned u = x.u;
    unsigned r = (u + 0x7fffu + ((u >> 16) & 1u)) >> 16;  // RNE
    return (ushort)r;
}
__device__ __forceinline__ float b2f(ushort b) {
    union { unsigned u; float f; } x; x.u = ((unsigned)b) << 16; return x.f;
}

// ---- weight prep: fp32 -> bf16, transposed to WT[n][k] --------------------
__global__ void k_prep(const float* __restrict__ lin_w, const float* __restrict__ rel_w,
                       const float* __restrict__ root_w, const float* __restrict__ rel_l,
                       const float* __restrict__ root_l, ushort* __restrict__ wT) {
    int idx = blockIdx.x * 256 + threadIdx.x;
    if (idx < 7 * 16384) {
        int m = idx >> 14, r = idx & 16383;
        int n = r >> 7, k = r & 127;
        const float* src = (m == 0) ? lin_w
                         : (m <= 3 ? rel_w + (m - 1) * 16384 : root_w + (m - 4) * 16384);
        wT[idx] = f2b(src[k * 128 + n]);
    } else if (idx < 7 * 16384 + 2 * 8192) {
        int r = idx - 7 * 16384;
        int m = r >> 13, rr = r & 8191;
        int n = rr >> 7, k = rr & 127;
        const float* src = m ? root_l : rel_l;
        wT[idx] = f2b(src[k * 64 + n]);
    }
}

// ---- CSR build ------------------------------------------------------------
__global__ void k_hist(const int* __restrict__ ei, int* __restrict__ deg) {
    int e = blockIdx.x * 256 + threadIdx.x;
    if (e < NE) atomicAdd(&deg[ei[NE + e]], 1);
}

__global__ void k_scan(const int* __restrict__ deg, int* __restrict__ offs,
                       int* __restrict__ cursor) {
    __shared__ int ssum[1024];
    int t = threadIdx.x;
    const int CH = 49;  // 1024*49 >= 50000
    int lo = t * CH, hi = min(lo + CH, NN);
    int s = 0;
    for (int n = lo; n < hi; n++) s += deg[n];
    ssum[t] = s;
    __syncthreads();
    for (int d = 1; d < 1024; d <<= 1) {
        int v = 0;
        if (t >= d) v = ssum[t - d];
        __syncthreads();
        ssum[t] += v;
        __syncthreads();
    }
    int base = ssum[t] - s;  // exclusive prefix
    for (int n = lo; n < hi; n++) {
        offs[n] = base; cursor[n] = base;
        base += deg[n];
    }
    if (t == 1023) offs[NN] = ssum[1023];
}

__global__ void k_fill(const int* __restrict__ ei, int* __restrict__ cursor,
                       int* __restrict__ csr) {
    int e = blockIdx.x * 256 + threadIdx.x;
    if (e < NE) {
        int d = ei[NE + e];
        int p = atomicAdd(&cursor[d], 1);
        csr[p] = ei[e];
    }
}

// ---- initial linear: h = bf16(x @ lin_w + lin_b) --------------------------
__global__ __launch_bounds__(256) void k_lin(const float* __restrict__ x,
                                             const ushort* __restrict__ wT,
                                             const float* __restrict__ bias,
                                             ushort* __restrict__ h) {
    int t = threadIdx.x;
    int lane = t & 63, wv = t >> 6;
    int node0 = (blockIdx.x * 4 + wv) * 16;
    int l15 = lane & 15, q = lane >> 4;
    int nA = min(node0 + l15, NN - 1);
    f4 acc[8];
#pragma unroll
    for (int nt = 0; nt < 8; nt++) acc[nt] = (f4)0.0f;
#pragma unroll
    for (int ks = 0; ks < 4; ks++) {
        const float* ap = x + nA * HID + ks * 32 + q * 8;
        bfrag a;
#pragma unroll
        for (int j = 0; j < 8; j++) a[j] = (short)f2b(ap[j]);
#pragma unroll
        for (int nt = 0; nt < 8; nt++) {
            bfrag b = *(const bfrag*)(wT + (nt * 16 + l15) * HID + ks * 32 + q * 8);
            acc[nt] = __builtin_amdgcn_mfma_f32_16x16x32_bf16(a, b, acc[nt], 0, 0, 0);
        }
    }
#pragma unroll
    for (int nt = 0; nt < 8; nt++) {
        int c = nt * 16 + l15;
        float bs = bias[c];
#pragma unroll
        for (int r = 0; r < 4; r++) {
            int node = node0 + q * 4 + r;
            if (node < NN) h[node * HID + c] = f2b(acc[nt][r] + bs);
        }
    }
}

// ---- aggregation: agg[n] = sum_{e in CSR[n]} h[src[e]] --------------------
__global__ __launch_bounds__(256) void k_agg(const ushort* __restrict__ h,
                                             const int* __restrict__ offs,
                                             const int* __restrict__ csr,
                                             ushort* __restrict__ agg) {
    int gw = (blockIdx.x * 256 + threadIdx.x) >> 6;  // one wave per node
    int lane = threadIdx.x & 63;
    if (gw >= NN) return;
    int e0 = offs[gw], e1 = offs[gw + 1];
    float ax = 0.f, ay = 0.f;
    for (int e = e0; e < e1; e++) {
        int s = csr[e];
        unsigned u = *(const unsigned*)(h + s * HID + lane * 2);
        ax += b2f((ushort)(u & 0xffffu));
        ay += b2f((ushort)(u >> 16));
    }
    unsigned o = ((unsigned)f2b(ay) << 16) | (unsigned)f2b(ax);
    *(unsigned*)(agg + gw * HID + lane * 2) = o;
}

// ---- conv layer: h2 = h + agg@rel + h@root + b; BN partial stats ----------
__global__ __launch_bounds__(256) void k_conv(const ushort* __restrict__ agg,
                                              const ushort* __restrict__ h,
                                              const ushort* __restrict__ relT,
                                              const ushort* __restrict__ rootT,
                                              const float* __restrict__ bias,
                                              float* __restrict__ bnacc,
                                              ushort* __restrict__ h2) {
    __shared__ float lsum[HID], lsq[HID];
    int t = threadIdx.x;
    if (t < HID) { lsum[t] = 0.f; lsq[t] = 0.f; }
    __syncthreads();
    int lane = t & 63, wv = t >> 6;
    int node0 = (blockIdx.x * 4 + wv) * 16;
    int l15 = lane & 15, q = lane >> 4;
    int nA = min(node0 + l15, NN - 1);
    f4 acc[8];
#pragma unroll
    for (int nt = 0; nt < 8; nt++) acc[nt] = (f4)0.0f;
#pragma unroll
    for (int ks = 0; ks < 4; ks++) {
        bfrag a1 = *(const bfrag*)(agg + nA * HID + ks * 32 + q * 8);
        bfrag a2 = *(const bfrag*)(h + nA * HID + ks * 32 + q * 8);
#pragma unroll
        for (int nt = 0; nt < 8; nt++) {
            bfrag b1 = *(const bfrag*)(relT + (nt * 16 + l15) * HID + ks * 32 + q * 8);
            acc[nt] = __builtin_amdgcn_mfma_f32_16x16x32_bf16(a1, b1, acc[nt], 0, 0, 0);
            bfrag b2 = *(const bfrag*)(rootT + (nt * 16 + l15) * HID + ks * 32 + q * 8);
            acc[nt] = __builtin_amdgcn_mfma_f32_16x16x32_bf16(a2, b2, acc[nt], 0, 0, 0);
        }
    }
#pragma unroll
    for (int nt = 0; nt < 8; nt++) {
        int c = nt * 16 + l15;
        float bs = bias[c];
        float s = 0.f, s2 = 0.f;
#pragma unroll
        for (int r = 0; r < 4; r++) {
            int node = node0 + q * 4 + r;
            int nc = min(node, NN - 1);
            float v = acc[nt][r] + bs + b2f(h[nc * HID + c]);  // + residual
            if (node < NN) {
                h2[node * HID + c] = f2b(v);
                s += v; s2 += v * v;
            }
        }
        s += __shfl_xor(s, 16); s += __shfl_xor(s, 32);
        s2 += __shfl_xor(s2, 16); s2 += __shfl_xor(s2, 32);
        if (q == 0) { atomicAdd(&lsum[c], s); atomicAdd(&lsq[c], s2); }
    }
    __syncthreads();
    if (t < HID) {
        atomicAdd(&bnacc[t], lsum[t]);
        atomicAdd(&bnacc[HID + t], lsq[t]);
    }
}

// ---- BN finalize + relu: h = relu((h2-mean)*rsqrt(var+eps)*gamma+beta) ----
__global__ void k_bnrelu(const ushort* __restrict__ h2, const float* __restrict__ bnacc,
                         const float* __restrict__ gamma, const float* __restrict__ beta,
                         ushort* __restrict__ h) {
    int t = blockIdx.x * 256 + threadIdx.x;
    if (t >= NN * HID / 8) return;
    int c0 = (t * 8) & 127;
    bfrag v = *(const bfrag*)(h2 + t * 8);
    bfrag o;
#pragma unroll
    for (int j = 0; j < 8; j++) {
        int c = c0 + j;
        float mean = bnacc[c] * (1.0f / NN);
        float var = bnacc[HID + c] * (1.0f / NN) - mean * mean;
        float sc = gamma[c] * rsqrtf(var + BN_EPS);
        float sh = beta[c] - mean * sc;
        float x = b2f((ushort)v[j]) * sc + sh;
        o[j] = (short)f2b(fmaxf(x, 0.0f));
    }
    *(bfrag*)(h + t * 8) = o;
}

// ---- final conv 128->64, fp32 node outputs --------------------------------
__global__ __launch_bounds__(256) void k_final(const ushort* __restrict__ agg,
                                               const ushort* __restrict__ h,
                                               const ushort* __restrict__ relT,
                                               const ushort* __restrict__ rootT,
                                               const float* __restrict__ bias,
                                               float* __restrict__ outn) {
    int t = threadIdx.x;
    int lane = t & 63, wv = t >> 6;
    int node0 = (blockIdx.x * 4 + wv) * 16;
    int l15 = lane & 15, q = lane >> 4;
    int nA = min(node0 + l15, NN - 1);
    f4 acc[4];
#pragma unroll
    for (int nt = 0; nt < 4; nt++) acc[nt] = (f4)0.0f;
#pragma unroll
    for (int ks = 0; ks < 4; ks++) {
        bfrag a1 = *(const bfrag*)(agg + nA * HID + ks * 32 + q * 8);
        bfrag a2 = *(const bfrag*)(h + nA * HID + ks * 32 + q * 8);
#pragma unroll
        for (int nt = 0; nt < 4; nt++) {
            bfrag b1 = *(const bfrag*)(relT + (nt * 16 + l15) * HID + ks * 32 + q * 8);
            acc[nt] = __builtin_amdgcn_mfma_f32_16x16x32_bf16(a1, b1, acc[nt], 0, 0, 0);
            bfrag b2 = *(const bfrag*)(rootT + (nt * 16 + l15) * HID + ks * 32 + q * 8);
            acc[nt] = __builtin_amdgcn_mfma_f32_16x16x32_bf16(a2, b2, acc[nt], 0, 0, 0);
        }
    }
#pragma unroll
    for (int nt = 0; nt < 4; nt++) {
        int c = nt * 16 + l15;
        float bs = bias[c];
#pragma unroll
        for (int r = 0; r < 4; r++) {
            int node = node0 + q * 4 + r;
            if (node < NN) outn[node * OUTC + c] = acc[nt][r] + bs;
        }
    }
}

// ---- global add pool (batch is sorted) ------------------------------------
__global__ void k_pool(const float* __restrict__ outn, const int* __restrict__ batch,
                       float* __restrict__ out) {
    int c = threadIdx.x;  // 0..63
    int n0 = blockIdx.x * 512;
    int n1 = min(n0 + 512, NN);
    if (n0 >= NN) return;
    float acc = 0.f;
    int g = batch[n0];
    for (int n = n0; n < n1; n++) {
        int gn = batch[n];
        if (gn != g) {
            atomicAdd(&out[g * OUTC + c], acc);
            acc = 0.f; g = gn;
        }
        acc += outn[n * OUTC + c];
    }
    atomicAdd(&out[g * OUTC + c], acc);
}

extern "C" void kernel_launch(void* const* d_in, const int* in_sizes, int n_in,
                              void* d_out, int out_size, void* d_ws, size_t ws_size,
                              hipStream_t stream) {
    const float* x      = (const float*)d_in[0];
    const int*   ei     = (const int*)d_in[1];
    const int*   batch  = (const int*)d_in[2];
    const float* lin_w  = (const float*)d_in[3];
    const float* lin_b  = (const float*)d_in[4];
    const float* rel_w  = (const float*)d_in[5];
    const float* root_w = (const float*)d_in[6];
    const float* conv_b = (const float*)d_in[7];
    const float* bn_g   = (const float*)d_in[8];
    const float* bn_b   = (const float*)d_in[9];
    const float* rel_l  = (const float*)d_in[10];
    const float* root_l = (const float*)d_in[11];
    const float* b_l    = (const float*)d_in[12];
    float* out = (float*)d_out;

    char* w = (char*)d_ws;
    ushort* h   = (ushort*)w; w += (size_t)NN * HID * 2;   // 12.8 MB bf16
    ushort* agg = (ushort*)w; w += (size_t)NN * HID * 2;   // 12.8 MB bf16
    ushort* h2  = (ushort*)w; w += (size_t)NN * HID * 2;   // 12.8 MB (also outn fp32: 50000*64*4)
    int* csr    = (int*)w;    w += (size_t)NE * 4;         // 3.2 MB
    int* deg    = (int*)w;    w += 200064;
    int* cursor = (int*)w;    w += 200064;
    int* offs   = (int*)w;    w += 200064;
    float* bnacc= (float*)w;  w += 3072;
    ushort* wT  = (ushort*)w; w += 131072 * 2;
    float* outn = (float*)h2;

    hipMemsetAsync(deg, 0, NN * sizeof(int), stream);
    hipMemsetAsync(bnacc, 0, NLAY * 2 * HID * sizeof(float), stream);
    hipMemsetAsync(out, 0, NG * OUTC * sizeof(float), stream);

    k_prep<<<512, 256, 0, stream>>>(lin_w, rel_w, root_w, rel_l, root_l, wT);
    k_hist<<<(NE + 255) / 256, 256, 0, stream>>>(ei, deg);
    k_scan<<<1, 1024, 0, stream>>>(deg, offs, cursor);
    k_fill<<<(NE + 255) / 256, 256, 0, stream>>>(ei, cursor, csr);

    int gemm_blocks = (NN + 63) / 64;  // 782
    k_lin<<<gemm_blocks, 256, 0, stream>>>(x, wT, lin_b, h);

    for (int i = 0; i < NLAY; i++) {
        k_agg<<<(NN + 3) / 4, 256, 0, stream>>>(h, offs, csr, agg);
        k_conv<<<gemm_blocks, 256, 0, stream>>>(agg, h,
                                                wT + 16384 + i * 16384,
                                                wT + 65536 + i * 16384,
                                                conv_b + i * HID, bnacc + i * 2 * HID, h2);
        k_bnrelu<<<(NN * HID / 8 + 255) / 256, 256, 0, stream>>>(
            h2, bnacc + i * 2 * HID, bn_g + i * HID, bn_b + i * HID, h);
    }

    k_agg<<<(NN + 3) / 4, 256, 0, stream>>>(h, offs, csr, agg);
    k_final<<<gemm_blocks, 256, 0, stream>>>(agg, h, wT + 114688, wT + 122880, b_l, outn);
    k_pool<<<(NN + 511) / 512, 64, 0, stream>>>(outn, batch, out);
}

// Round 2
// 689.605 us; speedup vs baseline: 1.4498x; 1.4498x over previous
//
#include <hip/hip_runtime.h>

#define NN 50000
#define NE 800000
#define HID 128
#define OUTC 64
#define NG 128
#define NLAY 3
#define BN_EPS 1e-5f

typedef __attribute__((ext_vector_type(8))) short bfrag;
typedef __attribute__((ext_vector_type(4))) float f4;

__device__ __forceinline__ ushort f2b(float f) {
    union { float f; unsigned u; } x; x.f = f;
    unsigned u = x.u;
    unsigned r = (u + 0x7fffu + ((u >> 16) & 1u)) >> 16;  // RNE
    return (ushort)r;
}
__device__ __forceinline__ float b2f(ushort b) {
    union { unsigned u; float f; } x; x.u = ((unsigned)b) << 16; return x.f;
}

// ---- weight prep: fp32 -> bf16, transposed to WT[n][k] --------------------
__global__ void k_prep(const float* __restrict__ lin_w, const float* __restrict__ rel_w,
                       const float* __restrict__ root_w, const float* __restrict__ rel_l,
                       const float* __restrict__ root_l, ushort* __restrict__ wT) {
    int idx = blockIdx.x * 256 + threadIdx.x;
    if (idx < 7 * 16384) {
        int m = idx >> 14, r = idx & 16383;
        int n = r >> 7, k = r & 127;
        const float* src = (m == 0) ? lin_w
                         : (m <= 3 ? rel_w + (m - 1) * 16384 : root_w + (m - 4) * 16384);
        wT[idx] = f2b(src[k * 128 + n]);
    } else if (idx < 7 * 16384 + 2 * 8192) {
        int r = idx - 7 * 16384;
        int m = r >> 13, rr = r & 8191;
        int n = rr >> 7, k = rr & 127;
        const float* src = m ? root_l : rel_l;
        wT[idx] = f2b(src[k * 64 + n]);
    }
}

// ---- CSR build ------------------------------------------------------------
__global__ void k_hist(const int* __restrict__ ei, int* __restrict__ deg) {
    int e = blockIdx.x * 256 + threadIdx.x;
    if (e < NE) atomicAdd(&deg[ei[NE + e]], 1);
}

__global__ void k_scan(const int* __restrict__ deg, int* __restrict__ offs,
                       int* __restrict__ cursor) {
    __shared__ int ssum[1024];
    int t = threadIdx.x;
    const int CH = 49;  // 1024*49 >= 50000
    int lo = t * CH, hi = min(lo + CH, NN);
    int s = 0;
    for (int n = lo; n < hi; n++) s += deg[n];
    ssum[t] = s;
    __syncthreads();
    for (int d = 1; d < 1024; d <<= 1) {
        int v = 0;
        if (t >= d) v = ssum[t - d];
        __syncthreads();
        ssum[t] += v;
        __syncthreads();
    }
    int base = ssum[t] - s;  // exclusive prefix
    for (int n = lo; n < hi; n++) {
        offs[n] = base; cursor[n] = base;
        base += deg[n];
    }
    if (t == 1023) offs[NN] = ssum[1023];
}

__global__ void k_fill(const int* __restrict__ ei, int* __restrict__ cursor,
                       int* __restrict__ csr) {
    int e = blockIdx.x * 256 + threadIdx.x;
    if (e < NE) {
        int d = ei[NE + e];
        int p = atomicAdd(&cursor[d], 1);
        csr[p] = ei[e];
    }
}

// ---- initial linear: h = bf16(x @ lin_w + lin_b) --------------------------
__global__ __launch_bounds__(256) void k_lin(const float* __restrict__ x,
                                             const ushort* __restrict__ wT,
                                             const float* __restrict__ bias,
                                             ushort* __restrict__ h) {
    int t = threadIdx.x;
    int lane = t & 63, wv = t >> 6;
    int node0 = (blockIdx.x * 4 + wv) * 16;
    int l15 = lane & 15, q = lane >> 4;
    int nA = min(node0 + l15, NN - 1);
    f4 acc[8];
#pragma unroll
    for (int nt = 0; nt < 8; nt++) acc[nt] = (f4)0.0f;
#pragma unroll
    for (int ks = 0; ks < 4; ks++) {
        const float* ap = x + nA * HID + ks * 32 + q * 8;
        bfrag a;
#pragma unroll
        for (int j = 0; j < 8; j++) a[j] = (short)f2b(ap[j]);
#pragma unroll
        for (int nt = 0; nt < 8; nt++) {
            bfrag b = *(const bfrag*)(wT + (nt * 16 + l15) * HID + ks * 32 + q * 8);
            acc[nt] = __builtin_amdgcn_mfma_f32_16x16x32_bf16(a, b, acc[nt], 0, 0, 0);
        }
    }
#pragma unroll
    for (int nt = 0; nt < 8; nt++) {
        int c = nt * 16 + l15;
        float bs = bias[c];
#pragma unroll
        for (int r = 0; r < 4; r++) {
            int node = node0 + q * 4 + r;
            if (node < NN) h[node * HID + c] = f2b(acc[nt][r] + bs);
        }
    }
}

// ---- aggregation: agg[n] = sum_{e in CSR[n]} h[src[e]] --------------------
__global__ __launch_bounds__(256) void k_agg(const ushort* __restrict__ h,
                                             const int* __restrict__ offs,
                                             const int* __restrict__ csr,
                                             ushort* __restrict__ agg) {
    int gw = (blockIdx.x * 256 + threadIdx.x) >> 6;  // one wave per node
    int lane = threadIdx.x & 63;
    if (gw >= NN) return;
    int e0 = offs[gw], e1 = offs[gw + 1];
    float ax = 0.f, ay = 0.f;
    int e = e0;
    for (; e + 4 <= e1; e += 4) {
        int s0 = csr[e], s1 = csr[e + 1], s2 = csr[e + 2], s3 = csr[e + 3];
        unsigned u0 = *(const unsigned*)(h + s0 * HID + lane * 2);
        unsigned u1 = *(const unsigned*)(h + s1 * HID + lane * 2);
        unsigned u2 = *(const unsigned*)(h + s2 * HID + lane * 2);
        unsigned u3 = *(const unsigned*)(h + s3 * HID + lane * 2);
        ax += b2f((ushort)(u0 & 0xffffu)) + b2f((ushort)(u1 & 0xffffu))
            + b2f((ushort)(u2 & 0xffffu)) + b2f((ushort)(u3 & 0xffffu));
        ay += b2f((ushort)(u0 >> 16)) + b2f((ushort)(u1 >> 16))
            + b2f((ushort)(u2 >> 16)) + b2f((ushort)(u3 >> 16));
    }
    for (; e < e1; e++) {
        int s = csr[e];
        unsigned u = *(const unsigned*)(h + s * HID + lane * 2);
        ax += b2f((ushort)(u & 0xffffu));
        ay += b2f((ushort)(u >> 16));
    }
    unsigned o = ((unsigned)f2b(ay) << 16) | (unsigned)f2b(ax);
    *(unsigned*)(agg + gw * HID + lane * 2) = o;
}

// ---- conv layer: h2 = h + agg@rel + h@root + b; BN partial stats ----------
__global__ __launch_bounds__(256) void k_conv(const ushort* __restrict__ agg,
                                              const ushort* __restrict__ h,
                                              const ushort* __restrict__ relT,
                                              const ushort* __restrict__ rootT,
                                              const float* __restrict__ bias,
                                              float* __restrict__ bnacc,
                                              ushort* __restrict__ h2) {
    __shared__ float lsum[HID], lsq[HID];
    int t = threadIdx.x;
    if (t < HID) { lsum[t] = 0.f; lsq[t] = 0.f; }
    __syncthreads();
    int lane = t & 63, wv = t >> 6;
    int node0 = (blockIdx.x * 4 + wv) * 16;
    int l15 = lane & 15, q = lane >> 4;
    int nA = min(node0 + l15, NN - 1);
    f4 acc[8];
#pragma unroll
    for (int nt = 0; nt < 8; nt++) acc[nt] = (f4)0.0f;
#pragma unroll
    for (int ks = 0; ks < 4; ks++) {
        bfrag a1 = *(const bfrag*)(agg + nA * HID + ks * 32 + q * 8);
        bfrag a2 = *(const bfrag*)(h + nA * HID + ks * 32 + q * 8);
#pragma unroll
        for (int nt = 0; nt < 8; nt++) {
            bfrag b1 = *(const bfrag*)(relT + (nt * 16 + l15) * HID + ks * 32 + q * 8);
            acc[nt] = __builtin_amdgcn_mfma_f32_16x16x32_bf16(a1, b1, acc[nt], 0, 0, 0);
            bfrag b2 = *(const bfrag*)(rootT + (nt * 16 + l15) * HID + ks * 32 + q * 8);
            acc[nt] = __builtin_amdgcn_mfma_f32_16x16x32_bf16(a2, b2, acc[nt], 0, 0, 0);
        }
    }
#pragma unroll
    for (int nt = 0; nt < 8; nt++) {
        int c = nt * 16 + l15;
        float bs = bias[c];
        float s = 0.f, s2 = 0.f;
#pragma unroll
        for (int r = 0; r < 4; r++) {
            int node = node0 + q * 4 + r;
            int nc = min(node, NN - 1);
            float v = acc[nt][r] + bs + b2f(h[nc * HID + c]);  // + residual
            if (node < NN) {
                h2[node * HID + c] = f2b(v);
                s += v; s2 += v * v;
            }
        }
        s += __shfl_xor(s, 16); s += __shfl_xor(s, 32);
        s2 += __shfl_xor(s2, 16); s2 += __shfl_xor(s2, 32);
        if (q == 0) { atomicAdd(&lsum[c], s); atomicAdd(&lsq[c], s2); }
    }
    __syncthreads();
    if (t < HID) {
        atomicAdd(&bnacc[t], lsum[t]);
        atomicAdd(&bnacc[HID + t], lsq[t]);
    }
}

// ---- BN finalize + relu: h = relu((h2-mean)*rsqrt(var+eps)*gamma+beta) ----
__global__ void k_bnrelu(const ushort* __restrict__ h2, const float* __restrict__ bnacc,
                         const float* __restrict__ gamma, const float* __restrict__ beta,
                         ushort* __restrict__ h) {
    int t = blockIdx.x * 256 + threadIdx.x;
    if (t >= NN * HID / 8) return;
    int c0 = (t * 8) & 127;
    bfrag v = *(const bfrag*)(h2 + t * 8);
    bfrag o;
#pragma unroll
    for (int j = 0; j < 8; j++) {
        int c = c0 + j;
        float mean = bnacc[c] * (1.0f / NN);
        float var = bnacc[HID + c] * (1.0f / NN) - mean * mean;
        float sc = gamma[c] * rsqrtf(var + BN_EPS);
        float sh = beta[c] - mean * sc;
        float x = b2f((ushort)v[j]) * sc + sh;
        o[j] = (short)f2b(fmaxf(x, 0.0f));
    }
    *(bfrag*)(h + t * 8) = o;
}

// ---- final conv 128->64, fp32 node outputs --------------------------------
__global__ __launch_bounds__(256) void k_final(const ushort* __restrict__ agg,
                                               const ushort* __restrict__ h,
                                               const ushort* __restrict__ relT,
                                               const ushort* __restrict__ rootT,
                                               const float* __restrict__ bias,
                                               float* __restrict__ outn) {
    int t = threadIdx.x;
    int lane = t & 63, wv = t >> 6;
    int node0 = (blockIdx.x * 4 + wv) * 16;
    int l15 = lane & 15, q = lane >> 4;
    int nA = min(node0 + l15, NN - 1);
    f4 acc[4];
#pragma unroll
    for (int nt = 0; nt < 4; nt++) acc[nt] = (f4)0.0f;
#pragma unroll
    for (int ks = 0; ks < 4; ks++) {
        bfrag a1 = *(const bfrag*)(agg + nA * HID + ks * 32 + q * 8);
        bfrag a2 = *(const bfrag*)(h + nA * HID + ks * 32 + q * 8);
#pragma unroll
        for (int nt = 0; nt < 4; nt++) {
            bfrag b1 = *(const bfrag*)(relT + (nt * 16 + l15) * HID + ks * 32 + q * 8);
            acc[nt] = __builtin_amdgcn_mfma_f32_16x16x32_bf16(a1, b1, acc[nt], 0, 0, 0);
            bfrag b2 = *(const bfrag*)(rootT + (nt * 16 + l15) * HID + ks * 32 + q * 8);
            acc[nt] = __builtin_amdgcn_mfma_f32_16x16x32_bf16(a2, b2, acc[nt], 0, 0, 0);
        }
    }
#pragma unroll
    for (int nt = 0; nt < 4; nt++) {
        int c = nt * 16 + l15;
        float bs = bias[c];
#pragma unroll
        for (int r = 0; r < 4; r++) {
            int node = node0 + q * 4 + r;
            if (node < NN) outn[node * OUTC + c] = acc[nt][r] + bs;
        }
    }
}

// ---- global add pool (batch is sorted): 32 nodes per wave -----------------
__global__ __launch_bounds__(64) void k_pool(const float* __restrict__ outn,
                                             const int* __restrict__ batch,
                                             float* __restrict__ out) {
    int c = threadIdx.x;  // 0..63 channel
    int n0 = blockIdx.x * 32;
    int n1 = min(n0 + 32, NN);
    if (n0 >= NN) return;
    float acc = 0.f;
    int g = batch[n0];
#pragma unroll 4
    for (int n = n0; n < n1; n++) {
        int gn = batch[n];
        if (gn != g) {
            atomicAdd(&out[g * OUTC + c], acc);
            acc = 0.f; g = gn;
        }
        acc += outn[n * OUTC + c];
    }
    atomicAdd(&out[g * OUTC + c], acc);
}

extern "C" void kernel_launch(void* const* d_in, const int* in_sizes, int n_in,
                              void* d_out, int out_size, void* d_ws, size_t ws_size,
                              hipStream_t stream) {
    const float* x      = (const float*)d_in[0];
    const int*   ei     = (const int*)d_in[1];
    const int*   batch  = (const int*)d_in[2];
    const float* lin_w  = (const float*)d_in[3];
    const float* lin_b  = (const float*)d_in[4];
    const float* rel_w  = (const float*)d_in[5];
    const float* root_w = (const float*)d_in[6];
    const float* conv_b = (const float*)d_in[7];
    const float* bn_g   = (const float*)d_in[8];
    const float* bn_b   = (const float*)d_in[9];
    const float* rel_l  = (const float*)d_in[10];
    const float* root_l = (const float*)d_in[11];
    const float* b_l    = (const float*)d_in[12];
    float* out = (float*)d_out;

    char* w = (char*)d_ws;
    ushort* h   = (ushort*)w; w += (size_t)NN * HID * 2;   // 12.8 MB bf16
    ushort* agg = (ushort*)w; w += (size_t)NN * HID * 2;   // 12.8 MB bf16
    ushort* h2  = (ushort*)w; w += (size_t)NN * HID * 2;   // 12.8 MB (also outn fp32: 50000*64*4)
    int* csr    = (int*)w;    w += (size_t)NE * 4;         // 3.2 MB
    int* deg    = (int*)w;    w += 200064;
    int* cursor = (int*)w;    w += 200064;
    int* offs   = (int*)w;    w += 200064;
    float* bnacc= (float*)w;  w += 3072;
    ushort* wT  = (ushort*)w; w += 131072 * 2;
    float* outn = (float*)h2;

    hipMemsetAsync(deg, 0, NN * sizeof(int), stream);
    hipMemsetAsync(bnacc, 0, NLAY * 2 * HID * sizeof(float), stream);
    hipMemsetAsync(out, 0, NG * OUTC * sizeof(float), stream);

    k_prep<<<512, 256, 0, stream>>>(lin_w, rel_w, root_w, rel_l, root_l, wT);
    k_hist<<<(NE + 255) / 256, 256, 0, stream>>>(ei, deg);
    k_scan<<<1, 1024, 0, stream>>>(deg, offs, cursor);
    k_fill<<<(NE + 255) / 256, 256, 0, stream>>>(ei, cursor, csr);

    int gemm_blocks = (NN + 63) / 64;  // 782
    k_lin<<<gemm_blocks, 256, 0, stream>>>(x, wT, lin_b, h);

    for (int i = 0; i < NLAY; i++) {
        k_agg<<<(NN + 3) / 4, 256, 0, stream>>>(h, offs, csr, agg);
        k_conv<<<gemm_blocks, 256, 0, stream>>>(agg, h,
                                                wT + 16384 + i * 16384,
                                                wT + 65536 + i * 16384,
                                                conv_b + i * HID, bnacc + i * 2 * HID, h2);
        k_bnrelu<<<(NN * HID / 8 + 255) / 256, 256, 0, stream>>>(
            h2, bnacc + i * 2 * HID, bn_g + i * HID, bn_b + i * HID, h);
    }

    k_agg<<<(NN + 3) / 4, 256, 0, stream>>>(h, offs, csr, agg);
    k_final<<<gemm_blocks, 256, 0, stream>>>(agg, h, wT + 114688, wT + 122880, b_l, outn);
    k_pool<<<(NN + 31) / 32, 64, 0, stream>>>(outn, batch, out);
}

// Round 3
// 593.128 us; speedup vs baseline: 1.6856x; 1.1627x over previous
//
#include <hip/hip_runtime.h>

#define NN 50000
#define NE 800000
#define HID 128
#define OUTC 64
#define NG 128
#define NLAY 3
#define BN_EPS 1e-5f
#define NBLK 196  // ceil(NN/256)

typedef __attribute__((ext_vector_type(8))) short bfrag;
typedef __attribute__((ext_vector_type(4))) float f4;

__device__ __forceinline__ ushort f2b(float f) {
    union { float f; unsigned u; } x; x.f = f;
    unsigned u = x.u;
    unsigned r = (u + 0x7fffu + ((u >> 16) & 1u)) >> 16;  // RNE
    return (ushort)r;
}
__device__ __forceinline__ float b2f(ushort b) {
    union { unsigned u; float f; } x; x.u = ((unsigned)b) << 16; return x.f;
}

// ---- weight prep: fp32 -> bf16, transposed to WT[n][k] --------------------
__global__ void k_prep(const float* __restrict__ lin_w, const float* __restrict__ rel_w,
                       const float* __restrict__ root_w, const float* __restrict__ rel_l,
                       const float* __restrict__ root_l, ushort* __restrict__ wT) {
    int idx = blockIdx.x * 256 + threadIdx.x;
    if (idx < 7 * 16384) {
        int m = idx >> 14, r = idx & 16383;
        int n = r >> 7, k = r & 127;
        const float* src = (m == 0) ? lin_w
                         : (m <= 3 ? rel_w + (m - 1) * 16384 : root_w + (m - 4) * 16384);
        wT[idx] = f2b(src[k * 128 + n]);
    } else if (idx < 7 * 16384 + 2 * 8192) {
        int r = idx - 7 * 16384;
        int m = r >> 13, rr = r & 8191;
        int n = rr >> 7, k = rr & 127;
        const float* src = m ? root_l : rel_l;
        wT[idx] = f2b(src[k * 64 + n]);
    }
}

// ---- CSR build ------------------------------------------------------------
__global__ void k_hist(const int* __restrict__ ei, int* __restrict__ deg) {
    int e = blockIdx.x * 256 + threadIdx.x;
    if (e < NE) atomicAdd(&deg[ei[NE + e]], 1);
}

// phase 1: per-block sums of deg (196 blocks x 256)
__global__ void k_bsum(const int* __restrict__ deg, int* __restrict__ bsum) {
    __shared__ int s[256];
    int t = threadIdx.x;
    int n = blockIdx.x * 256 + t;
    s[t] = (n < NN) ? deg[n] : 0;
    __syncthreads();
    for (int d = 128; d > 0; d >>= 1) {
        if (t < d) s[t] += s[t + d];
        __syncthreads();
    }
    if (t == 0) bsum[blockIdx.x] = s[0];
}

// phase 2: exclusive scan of 196 block sums (1 block)
__global__ void k_scanb(int* __restrict__ bsum, int* __restrict__ offs) {
    __shared__ int s[256];
    int t = threadIdx.x;
    int v = (t < NBLK) ? bsum[t] : 0;
    s[t] = v;
    __syncthreads();
    for (int d = 1; d < 256; d <<= 1) {
        int u = 0;
        if (t >= d) u = s[t - d];
        __syncthreads();
        s[t] += u;
        __syncthreads();
    }
    if (t < NBLK) bsum[t] = s[t] - v;  // exclusive prefix
    if (t == 0) offs[NN] = NE;
}

// phase 3: per-node exclusive prefix = block-scan(deg) + block prefix
__global__ void k_offs(const int* __restrict__ deg, const int* __restrict__ bsum,
                       int* __restrict__ offs, int* __restrict__ cursor) {
    __shared__ int s[256];
    int t = threadIdx.x;
    int n = blockIdx.x * 256 + t;
    int v = (n < NN) ? deg[n] : 0;
    s[t] = v;
    __syncthreads();
    for (int d = 1; d < 256; d <<= 1) {
        int u = 0;
        if (t >= d) u = s[t - d];
        __syncthreads();
        s[t] += u;
        __syncthreads();
    }
    if (n < NN) {
        int excl = s[t] - v + bsum[blockIdx.x];
        offs[n] = excl;
        cursor[n] = excl;
    }
}

__global__ void k_fill(const int* __restrict__ ei, int* __restrict__ cursor,
                       int* __restrict__ csr) {
    int e = blockIdx.x * 256 + threadIdx.x;
    if (e < NE) {
        int d = ei[NE + e];
        int p = atomicAdd(&cursor[d], 1);
        csr[p] = ei[e];
    }
}

// ---- initial linear: h = bf16(x @ lin_w + lin_b) --------------------------
__global__ __launch_bounds__(256) void k_lin(const float* __restrict__ x,
                                             const ushort* __restrict__ wT,
                                             const float* __restrict__ bias,
                                             ushort* __restrict__ h) {
    int t = threadIdx.x;
    int lane = t & 63, wv = t >> 6;
    int node0 = (blockIdx.x * 4 + wv) * 16;
    int l15 = lane & 15, q = lane >> 4;
    int nA = min(node0 + l15, NN - 1);
    f4 acc[8];
#pragma unroll
    for (int nt = 0; nt < 8; nt++) acc[nt] = (f4)0.0f;
#pragma unroll
    for (int ks = 0; ks < 4; ks++) {
        const float* ap = x + nA * HID + ks * 32 + q * 8;
        bfrag a;
#pragma unroll
        for (int j = 0; j < 8; j++) a[j] = (short)f2b(ap[j]);
#pragma unroll
        for (int nt = 0; nt < 8; nt++) {
            bfrag b = *(const bfrag*)(wT + (nt * 16 + l15) * HID + ks * 32 + q * 8);
            acc[nt] = __builtin_amdgcn_mfma_f32_16x16x32_bf16(a, b, acc[nt], 0, 0, 0);
        }
    }
#pragma unroll
    for (int nt = 0; nt < 8; nt++) {
        int c = nt * 16 + l15;
        float bs = bias[c];
#pragma unroll
        for (int r = 0; r < 4; r++) {
            int node = node0 + q * 4 + r;
            if (node < NN) h[node * HID + c] = f2b(acc[nt][r] + bs);
        }
    }
}

// ---- aggregation: agg[n] = sum_{e in CSR[n]} h[src[e]] --------------------
__global__ __launch_bounds__(256) void k_agg(const ushort* __restrict__ h,
                                             const int* __restrict__ offs,
                                             const int* __restrict__ csr,
                                             ushort* __restrict__ agg) {
    int gw = (blockIdx.x * 256 + threadIdx.x) >> 6;  // one wave per node
    int lane = threadIdx.x & 63;
    if (gw >= NN) return;
    int e0 = offs[gw], e1 = offs[gw + 1];
    float ax = 0.f, ay = 0.f;
    int e = e0;
    for (; e + 4 <= e1; e += 4) {
        int s0 = csr[e], s1 = csr[e + 1], s2 = csr[e + 2], s3 = csr[e + 3];
        unsigned u0 = *(const unsigned*)(h + s0 * HID + lane * 2);
        unsigned u1 = *(const unsigned*)(h + s1 * HID + lane * 2);
        unsigned u2 = *(const unsigned*)(h + s2 * HID + lane * 2);
        unsigned u3 = *(const unsigned*)(h + s3 * HID + lane * 2);
        ax += b2f((ushort)(u0 & 0xffffu)) + b2f((ushort)(u1 & 0xffffu))
            + b2f((ushort)(u2 & 0xffffu)) + b2f((ushort)(u3 & 0xffffu));
        ay += b2f((ushort)(u0 >> 16)) + b2f((ushort)(u1 >> 16))
            + b2f((ushort)(u2 >> 16)) + b2f((ushort)(u3 >> 16));
    }
    for (; e < e1; e++) {
        int s = csr[e];
        unsigned u = *(const unsigned*)(h + s * HID + lane * 2);
        ax += b2f((ushort)(u & 0xffffu));
        ay += b2f((ushort)(u >> 16));
    }
    unsigned o = ((unsigned)f2b(ay) << 16) | (unsigned)f2b(ax);
    *(unsigned*)(agg + gw * HID + lane * 2) = o;
}

// ---- conv layer: h2 = h + agg@rel + h@root + b; BN partial stats ----------
__global__ __launch_bounds__(256) void k_conv(const ushort* __restrict__ agg,
                                              const ushort* __restrict__ h,
                                              const ushort* __restrict__ relT,
                                              const ushort* __restrict__ rootT,
                                              const float* __restrict__ bias,
                                              float* __restrict__ bnacc,
                                              ushort* __restrict__ h2) {
    __shared__ float lsum[HID], lsq[HID];
    int t = threadIdx.x;
    if (t < HID) { lsum[t] = 0.f; lsq[t] = 0.f; }
    __syncthreads();
    int lane = t & 63, wv = t >> 6;
    int node0 = (blockIdx.x * 4 + wv) * 16;
    int l15 = lane & 15, q = lane >> 4;
    int nA = min(node0 + l15, NN - 1);
    f4 acc[8];
#pragma unroll
    for (int nt = 0; nt < 8; nt++) acc[nt] = (f4)0.0f;
#pragma unroll
    for (int ks = 0; ks < 4; ks++) {
        bfrag a1 = *(const bfrag*)(agg + nA * HID + ks * 32 + q * 8);
        bfrag a2 = *(const bfrag*)(h + nA * HID + ks * 32 + q * 8);
#pragma unroll
        for (int nt = 0; nt < 8; nt++) {
            bfrag b1 = *(const bfrag*)(relT + (nt * 16 + l15) * HID + ks * 32 + q * 8);
            acc[nt] = __builtin_amdgcn_mfma_f32_16x16x32_bf16(a1, b1, acc[nt], 0, 0, 0);
            bfrag b2 = *(const bfrag*)(rootT + (nt * 16 + l15) * HID + ks * 32 + q * 8);
            acc[nt] = __builtin_amdgcn_mfma_f32_16x16x32_bf16(a2, b2, acc[nt], 0, 0, 0);
        }
    }
#pragma unroll
    for (int nt = 0; nt < 8; nt++) {
        int c = nt * 16 + l15;
        float bs = bias[c];
        float s = 0.f, s2 = 0.f;
#pragma unroll
        for (int r = 0; r < 4; r++) {
            int node = node0 + q * 4 + r;
            int nc = min(node, NN - 1);
            float v = acc[nt][r] + bs + b2f(h[nc * HID + c]);  // + residual
            if (node < NN) {
                h2[node * HID + c] = f2b(v);
                s += v; s2 += v * v;
            }
        }
        s += __shfl_xor(s, 16); s += __shfl_xor(s, 32);
        s2 += __shfl_xor(s2, 16); s2 += __shfl_xor(s2, 32);
        if (q == 0) { atomicAdd(&lsum[c], s); atomicAdd(&lsq[c], s2); }
    }
    __syncthreads();
    if (t < HID) {
        atomicAdd(&bnacc[t], lsum[t]);
        atomicAdd(&bnacc[HID + t], lsq[t]);
    }
}

// ---- BN finalize + relu: h = relu((h2-mean)*rsqrt(var+eps)*gamma+beta) ----
__global__ void k_bnrelu(const ushort* __restrict__ h2, const float* __restrict__ bnacc,
                         const float* __restrict__ gamma, const float* __restrict__ beta,
                         ushort* __restrict__ h) {
    int t = blockIdx.x * 256 + threadIdx.x;
    if (t >= NN * HID / 8) return;
    int c0 = (t * 8) & 127;
    bfrag v = *(const bfrag*)(h2 + t * 8);
    bfrag o;
#pragma unroll
    for (int j = 0; j < 8; j++) {
        int c = c0 + j;
        float mean = bnacc[c] * (1.0f / NN);
        float var = bnacc[HID + c] * (1.0f / NN) - mean * mean;
        float sc = gamma[c] * rsqrtf(var + BN_EPS);
        float sh = beta[c] - mean * sc;
        float x = b2f((ushort)v[j]) * sc + sh;
        o[j] = (short)f2b(fmaxf(x, 0.0f));
    }
    *(bfrag*)(h + t * 8) = o;
}

// ---- final conv 128->64, fp32 node outputs --------------------------------
__global__ __launch_bounds__(256) void k_final(const ushort* __restrict__ agg,
                                               const ushort* __restrict__ h,
                                               const ushort* __restrict__ relT,
                                               const ushort* __restrict__ rootT,
                                               const float* __restrict__ bias,
                                               float* __restrict__ outn) {
    int t = threadIdx.x;
    int lane = t & 63, wv = t >> 6;
    int node0 = (blockIdx.x * 4 + wv) * 16;
    int l15 = lane & 15, q = lane >> 4;
    int nA = min(node0 + l15, NN - 1);
    f4 acc[4];
#pragma unroll
    for (int nt = 0; nt < 4; nt++) acc[nt] = (f4)0.0f;
#pragma unroll
    for (int ks = 0; ks < 4; ks++) {
        bfrag a1 = *(const bfrag*)(agg + nA * HID + ks * 32 + q * 8);
        bfrag a2 = *(const bfrag*)(h + nA * HID + ks * 32 + q * 8);
#pragma unroll
        for (int nt = 0; nt < 4; nt++) {
            bfrag b1 = *(const bfrag*)(relT + (nt * 16 + l15) * HID + ks * 32 + q * 8);
            acc[nt] = __builtin_amdgcn_mfma_f32_16x16x32_bf16(a1, b1, acc[nt], 0, 0, 0);
            bfrag b2 = *(const bfrag*)(rootT + (nt * 16 + l15) * HID + ks * 32 + q * 8);
            acc[nt] = __builtin_amdgcn_mfma_f32_16x16x32_bf16(a2, b2, acc[nt], 0, 0, 0);
        }
    }
#pragma unroll
    for (int nt = 0; nt < 4; nt++) {
        int c = nt * 16 + l15;
        float bs = bias[c];
#pragma unroll
        for (int r = 0; r < 4; r++) {
            int node = node0 + q * 4 + r;
            if (node < NN) outn[node * OUTC + c] = acc[nt][r] + bs;
        }
    }
}

// ---- global add pool (batch is sorted): 32 nodes per wave -----------------
__global__ __launch_bounds__(64) void k_pool(const float* __restrict__ outn,
                                             const int* __restrict__ batch,
                                             float* __restrict__ out) {
    int c = threadIdx.x;  // 0..63 channel
    int n0 = blockIdx.x * 32;
    int n1 = min(n0 + 32, NN);
    if (n0 >= NN) return;
    float acc = 0.f;
    int g = batch[n0];
#pragma unroll 4
    for (int n = n0; n < n1; n++) {
        int gn = batch[n];
        if (gn != g) {
            atomicAdd(&out[g * OUTC + c], acc);
            acc = 0.f; g = gn;
        }
        acc += outn[n * OUTC + c];
    }
    atomicAdd(&out[g * OUTC + c], acc);
}

extern "C" void kernel_launch(void* const* d_in, const int* in_sizes, int n_in,
                              void* d_out, int out_size, void* d_ws, size_t ws_size,
                              hipStream_t stream) {
    const float* x      = (const float*)d_in[0];
    const int*   ei     = (const int*)d_in[1];
    const int*   batch  = (const int*)d_in[2];
    const float* lin_w  = (const float*)d_in[3];
    const float* lin_b  = (const float*)d_in[4];
    const float* rel_w  = (const float*)d_in[5];
    const float* root_w = (const float*)d_in[6];
    const float* conv_b = (const float*)d_in[7];
    const float* bn_g   = (const float*)d_in[8];
    const float* bn_b   = (const float*)d_in[9];
    const float* rel_l  = (const float*)d_in[10];
    const float* root_l = (const float*)d_in[11];
    const float* b_l    = (const float*)d_in[12];
    float* out = (float*)d_out;

    char* w = (char*)d_ws;
    ushort* h   = (ushort*)w; w += (size_t)NN * HID * 2;   // 12.8 MB bf16
    ushort* agg = (ushort*)w; w += (size_t)NN * HID * 2;   // 12.8 MB bf16
    ushort* h2  = (ushort*)w; w += (size_t)NN * HID * 2;   // 12.8 MB (also outn fp32)
    int* csr    = (int*)w;    w += (size_t)NE * 4;         // 3.2 MB
    int* deg    = (int*)w;    w += 200064;
    int* cursor = (int*)w;    w += 200064;
    int* offs   = (int*)w;    w += 200064;
    float* bnacc= (float*)w;  w += 3072;
    int* bsum   = (int*)w;    w += 1024;
    ushort* wT  = (ushort*)w; w += 131072 * 2;
    float* outn = (float*)h2;

    hipMemsetAsync(deg, 0, NN * sizeof(int), stream);
    hipMemsetAsync(bnacc, 0, NLAY * 2 * HID * sizeof(float), stream);
    hipMemsetAsync(out, 0, NG * OUTC * sizeof(float), stream);

    k_prep<<<512, 256, 0, stream>>>(lin_w, rel_w, root_w, rel_l, root_l, wT);
    k_hist<<<(NE + 255) / 256, 256, 0, stream>>>(ei, deg);
    k_bsum<<<NBLK, 256, 0, stream>>>(deg, bsum);
    k_scanb<<<1, 256, 0, stream>>>(bsum, offs);
    k_offs<<<NBLK, 256, 0, stream>>>(deg, bsum, offs, cursor);
    k_fill<<<(NE + 255) / 256, 256, 0, stream>>>(ei, cursor, csr);

    int gemm_blocks = (NN + 63) / 64;  // 782
    k_lin<<<gemm_blocks, 256, 0, stream>>>(x, wT, lin_b, h);

    for (int i = 0; i < NLAY; i++) {
        k_agg<<<(NN + 3) / 4, 256, 0, stream>>>(h, offs, csr, agg);
        k_conv<<<gemm_blocks, 256, 0, stream>>>(agg, h,
                                                wT + 16384 + i * 16384,
                                                wT + 65536 + i * 16384,
                                                conv_b + i * HID, bnacc + i * 2 * HID, h2);
        k_bnrelu<<<(NN * HID / 8 + 255) / 256, 256, 0, stream>>>(
            h2, bnacc + i * 2 * HID, bn_g + i * HID, bn_b + i * HID, h);
    }

    k_agg<<<(NN + 3) / 4, 256, 0, stream>>>(h, offs, csr, agg);
    k_final<<<gemm_blocks, 256, 0, stream>>>(agg, h, wT + 114688, wT + 122880, b_l, outn);
    k_pool<<<(NN + 31) / 32, 64, 0, stream>>>(outn, batch, out);
}

// Round 4
// 517.945 us; speedup vs baseline: 1.9303x; 1.1452x over previous
//
#include <hip/hip_runtime.h>

#define NN 50000
#define NE 800000
#define HID 128
#define OUTC 64
#define NG 128
#define NLAY 3
#define BN_EPS 1e-5f
#define NBLK 196  // ceil(NN/256)

typedef __attribute__((ext_vector_type(8))) short bfrag;
typedef __attribute__((ext_vector_type(4))) float f4;

__device__ __forceinline__ ushort f2b(float f) {
    union { float f; unsigned u; } x; x.f = f;
    unsigned u = x.u;
    unsigned r = (u + 0x7fffu + ((u >> 16) & 1u)) >> 16;  // RNE
    return (ushort)r;
}
__device__ __forceinline__ float b2f(ushort b) {
    union { unsigned u; float f; } x; x.u = ((unsigned)b) << 16; return x.f;
}

// ---- weight prep: fp32 -> bf16, transposed to WT[n][k] --------------------
__global__ void k_prep(const float* __restrict__ lin_w, const float* __restrict__ rel_w,
                       const float* __restrict__ root_w, const float* __restrict__ rel_l,
                       const float* __restrict__ root_l, ushort* __restrict__ wT) {
    int idx = blockIdx.x * 256 + threadIdx.x;
    if (idx < 7 * 16384) {
        int m = idx >> 14, r = idx & 16383;
        int n = r >> 7, k = r & 127;
        const float* src = (m == 0) ? lin_w
                         : (m <= 3 ? rel_w + (m - 1) * 16384 : root_w + (m - 4) * 16384);
        wT[idx] = f2b(src[k * 128 + n]);
    } else if (idx < 7 * 16384 + 2 * 8192) {
        int r = idx - 7 * 16384;
        int m = r >> 13, rr = r & 8191;
        int n = rr >> 7, k = rr & 127;
        const float* src = m ? root_l : rel_l;
        wT[idx] = f2b(src[k * 64 + n]);
    }
}

// ---- CSR build ------------------------------------------------------------
__global__ void k_hist(const int* __restrict__ ei, int* __restrict__ deg) {
    int e = blockIdx.x * 256 + threadIdx.x;
    if (e < NE) atomicAdd(&deg[ei[NE + e]], 1);
}

__global__ void k_bsum(const int* __restrict__ deg, int* __restrict__ bsum) {
    __shared__ int s[256];
    int t = threadIdx.x;
    int n = blockIdx.x * 256 + t;
    s[t] = (n < NN) ? deg[n] : 0;
    __syncthreads();
    for (int d = 128; d > 0; d >>= 1) {
        if (t < d) s[t] += s[t + d];
        __syncthreads();
    }
    if (t == 0) bsum[blockIdx.x] = s[0];
}

__global__ void k_scanb(int* __restrict__ bsum, int* __restrict__ offs) {
    __shared__ int s[256];
    int t = threadIdx.x;
    int v = (t < NBLK) ? bsum[t] : 0;
    s[t] = v;
    __syncthreads();
    for (int d = 1; d < 256; d <<= 1) {
        int u = 0;
        if (t >= d) u = s[t - d];
        __syncthreads();
        s[t] += u;
        __syncthreads();
    }
    if (t < NBLK) bsum[t] = s[t] - v;
    if (t == 0) offs[NN] = NE;
}

__global__ void k_offs(const int* __restrict__ deg, const int* __restrict__ bsum,
                       int* __restrict__ offs, int* __restrict__ cursor) {
    __shared__ int s[256];
    int t = threadIdx.x;
    int n = blockIdx.x * 256 + t;
    int v = (n < NN) ? deg[n] : 0;
    s[t] = v;
    __syncthreads();
    for (int d = 1; d < 256; d <<= 1) {
        int u = 0;
        if (t >= d) u = s[t - d];
        __syncthreads();
        s[t] += u;
        __syncthreads();
    }
    if (n < NN) {
        int excl = s[t] - v + bsum[blockIdx.x];
        offs[n] = excl;
        cursor[n] = excl;
    }
}

__global__ void k_fill(const int* __restrict__ ei, int* __restrict__ cursor,
                       int* __restrict__ csr) {
    int e = blockIdx.x * 256 + threadIdx.x;
    if (e < NE) {
        int d = ei[NE + e];
        int p = atomicAdd(&cursor[d], 1);
        csr[p] = ei[e];
    }
}

// ---- initial linear: h = bf16(x @ lin_w + lin_b) --------------------------
__global__ __launch_bounds__(256) void k_lin(const float* __restrict__ x,
                                             const ushort* __restrict__ wT,
                                             const float* __restrict__ bias,
                                             ushort* __restrict__ h) {
    __shared__ __align__(16) ushort tp[4][16 * 136];
    int t = threadIdx.x;
    int lane = t & 63, wv = t >> 6;
    int node0 = (blockIdx.x * 4 + wv) * 16;
    int l15 = lane & 15, q = lane >> 4;
    int nA = min(node0 + l15, NN - 1);
    f4 acc[8];
#pragma unroll
    for (int nt = 0; nt < 8; nt++) acc[nt] = (f4)0.0f;
#pragma unroll
    for (int ks = 0; ks < 4; ks++) {
        const float* ap = x + (size_t)nA * HID + ks * 32 + q * 8;
        bfrag a;
#pragma unroll
        for (int j = 0; j < 8; j++) a[j] = (short)f2b(ap[j]);
#pragma unroll
        for (int nt = 0; nt < 8; nt++) {
            bfrag b = *(const bfrag*)(wT + (nt * 16 + l15) * HID + ks * 32 + q * 8);
            acc[nt] = __builtin_amdgcn_mfma_f32_16x16x32_bf16(a, b, acc[nt], 0, 0, 0);
        }
    }
#pragma unroll
    for (int nt = 0; nt < 8; nt++) {
        float bs = bias[nt * 16 + l15];
#pragma unroll
        for (int r = 0; r < 4; r++)
            tp[wv][(q * 4 + r) * 136 + nt * 16 + l15] = f2b(acc[nt][r] + bs);
    }
    __syncthreads();
#pragma unroll
    for (int i = 0; i < 4; i++) {
        int nr = node0 + i * 4 + q;
        if (nr < NN) {
            bfrag tv = *(const bfrag*)&tp[wv][(i * 4 + q) * 136 + l15 * 8];
            *(bfrag*)(h + (size_t)nr * HID + l15 * 8) = tv;
        }
    }
}

// ---- aggregation: 4 edges per wave, 16B/lane ------------------------------
__global__ __launch_bounds__(256) void k_agg(const ushort* __restrict__ h,
                                             const int* __restrict__ offs,
                                             const int* __restrict__ csr,
                                             ushort* __restrict__ agg) {
    int gw = (blockIdx.x * 256 + threadIdx.x) >> 6;  // one wave per node
    int lane = threadIdx.x & 63;
    int slot = lane >> 4, c16 = lane & 15;
    if (gw >= NN) return;
    int e0 = offs[gw], e1 = offs[gw + 1];
    float a[8];
#pragma unroll
    for (int j = 0; j < 8; j++) a[j] = 0.f;
    int base = e0;
    for (; base + 8 <= e1; base += 8) {
        int s0 = csr[base + slot];
        int s1 = csr[base + 4 + slot];
        bfrag v0 = *(const bfrag*)(h + (size_t)s0 * HID + c16 * 8);
        bfrag v1 = *(const bfrag*)(h + (size_t)s1 * HID + c16 * 8);
#pragma unroll
        for (int j = 0; j < 8; j++)
            a[j] += b2f((ushort)v0[j]) + b2f((ushort)v1[j]);
    }
    if (base + 4 <= e1) {
        int s0 = csr[base + slot];
        bfrag v0 = *(const bfrag*)(h + (size_t)s0 * HID + c16 * 8);
#pragma unroll
        for (int j = 0; j < 8; j++) a[j] += b2f((ushort)v0[j]);
        base += 4;
    }
    int rem = e1 - base;
    if (slot < rem) {
        int s0 = csr[base + slot];
        bfrag v0 = *(const bfrag*)(h + (size_t)s0 * HID + c16 * 8);
#pragma unroll
        for (int j = 0; j < 8; j++) a[j] += b2f((ushort)v0[j]);
    }
#pragma unroll
    for (int j = 0; j < 8; j++) {
        a[j] += __shfl_xor(a[j], 16);
        a[j] += __shfl_xor(a[j], 32);
    }
    if (slot == 0) {
        bfrag o;
#pragma unroll
        for (int j = 0; j < 8; j++) o[j] = (short)f2b(a[j]);
        *(bfrag*)(agg + (size_t)gw * HID + c16 * 8) = o;
    }
}

// ---- conv layer: h2 = h + agg@rel + h@root + b; sharded BN partials -------
__global__ __launch_bounds__(256) void k_conv(const ushort* __restrict__ agg,
                                              const ushort* __restrict__ h,
                                              const ushort* __restrict__ relT,
                                              const ushort* __restrict__ rootT,
                                              const float* __restrict__ bias,
                                              float* __restrict__ bn_sh,
                                              ushort* __restrict__ h2) {
    __shared__ __align__(16) ushort tp[4][16 * 136];
    __shared__ float lsum[256];
    int t = threadIdx.x;
    lsum[t] = 0.f;
    int lane = t & 63, wv = t >> 6;
    int node0 = (blockIdx.x * 4 + wv) * 16;
    int l15 = lane & 15, q = lane >> 4;
    int nA = min(node0 + l15, NN - 1);
    // prefetch residual rows (independent of MFMA loop -> high MLP)
    bfrag hres[4];
    int nr[4];
#pragma unroll
    for (int i = 0; i < 4; i++) {
        nr[i] = node0 + i * 4 + q;
        int nc = min(nr[i], NN - 1);
        hres[i] = *(const bfrag*)(h + (size_t)nc * HID + l15 * 8);
    }
    f4 acc[8];
#pragma unroll
    for (int nt = 0; nt < 8; nt++) acc[nt] = (f4)0.0f;
#pragma unroll
    for (int ks = 0; ks < 4; ks++) {
        bfrag a1 = *(const bfrag*)(agg + (size_t)nA * HID + ks * 32 + q * 8);
        bfrag a2 = *(const bfrag*)(h + (size_t)nA * HID + ks * 32 + q * 8);
#pragma unroll
        for (int nt = 0; nt < 8; nt++) {
            bfrag b1 = *(const bfrag*)(relT + (nt * 16 + l15) * HID + ks * 32 + q * 8);
            acc[nt] = __builtin_amdgcn_mfma_f32_16x16x32_bf16(a1, b1, acc[nt], 0, 0, 0);
            bfrag b2 = *(const bfrag*)(rootT + (nt * 16 + l15) * HID + ks * 32 + q * 8);
            acc[nt] = __builtin_amdgcn_mfma_f32_16x16x32_bf16(a2, b2, acc[nt], 0, 0, 0);
        }
    }
#pragma unroll
    for (int nt = 0; nt < 8; nt++) {
        float bs = bias[nt * 16 + l15];
#pragma unroll
        for (int r = 0; r < 4; r++)
            tp[wv][(q * 4 + r) * 136 + nt * 16 + l15] = f2b(acc[nt][r] + bs);
    }
    __syncthreads();
    float s[8], s2[8];
#pragma unroll
    for (int j = 0; j < 8; j++) { s[j] = 0.f; s2[j] = 0.f; }
#pragma unroll
    for (int i = 0; i < 4; i++) {
        bfrag tv = *(const bfrag*)&tp[wv][(i * 4 + q) * 136 + l15 * 8];
        float m = (nr[i] < NN) ? 1.0f : 0.0f;
        bfrag o;
#pragma unroll
        for (int j = 0; j < 8; j++) {
            float v = b2f((ushort)tv[j]) + b2f((ushort)hres[i][j]);
            o[j] = (short)f2b(v);
            s[j] += m * v;
            s2[j] += m * v * v;
        }
        if (nr[i] < NN) *(bfrag*)(h2 + (size_t)nr[i] * HID + l15 * 8) = o;
    }
#pragma unroll
    for (int j = 0; j < 8; j++) {
        s[j] += __shfl_xor(s[j], 16);  s[j] += __shfl_xor(s[j], 32);
        s2[j] += __shfl_xor(s2[j], 16); s2[j] += __shfl_xor(s2[j], 32);
    }
    if (q == 0) {
#pragma unroll
        for (int j = 0; j < 8; j++) {
            atomicAdd(&lsum[l15 * 8 + j], s[j]);
            atomicAdd(&lsum[128 + l15 * 8 + j], s2[j]);
        }
    }
    __syncthreads();
    atomicAdd(&bn_sh[(blockIdx.x & 63) * 256 + t], lsum[t]);
}

// ---- reduce 64 shards -> bnacc[256] for one layer -------------------------
__global__ void k_bnred(const float* __restrict__ bn_sh, float* __restrict__ bnacc) {
    int t = threadIdx.x;  // 256
    float s = 0.f;
#pragma unroll 8
    for (int k = 0; k < 64; k++) s += bn_sh[k * 256 + t];
    bnacc[t] = s;
}

// ---- BN finalize + relu ---------------------------------------------------
__global__ void k_bnrelu(const ushort* __restrict__ h2, const float* __restrict__ bnacc,
                         const float* __restrict__ gamma, const float* __restrict__ beta,
                         ushort* __restrict__ h) {
    int t = blockIdx.x * 256 + threadIdx.x;
    if (t >= NN * HID / 8) return;
    int c0 = (t * 8) & 127;
    bfrag v = *(const bfrag*)(h2 + (size_t)t * 8);
    bfrag o;
#pragma unroll
    for (int j = 0; j < 8; j++) {
        int c = c0 + j;
        float mean = bnacc[c] * (1.0f / NN);
        float var = bnacc[HID + c] * (1.0f / NN) - mean * mean;
        float sc = gamma[c] * rsqrtf(var + BN_EPS);
        float sh = beta[c] - mean * sc;
        float x = b2f((ushort)v[j]) * sc + sh;
        o[j] = (short)f2b(fmaxf(x, 0.0f));
    }
    *(bfrag*)(h + (size_t)t * 8) = o;
}

// ---- final conv 128->64, fp32 node outputs --------------------------------
__global__ __launch_bounds__(256) void k_final(const ushort* __restrict__ agg,
                                               const ushort* __restrict__ h,
                                               const ushort* __restrict__ relT,
                                               const ushort* __restrict__ rootT,
                                               const float* __restrict__ bias,
                                               float* __restrict__ outn) {
    __shared__ __align__(16) float tpf[4][16 * 68];
    int t = threadIdx.x;
    int lane = t & 63, wv = t >> 6;
    int node0 = (blockIdx.x * 4 + wv) * 16;
    int l15 = lane & 15, q = lane >> 4;
    int nA = min(node0 + l15, NN - 1);
    f4 acc[4];
#pragma unroll
    for (int nt = 0; nt < 4; nt++) acc[nt] = (f4)0.0f;
#pragma unroll
    for (int ks = 0; ks < 4; ks++) {
        bfrag a1 = *(const bfrag*)(agg + (size_t)nA * HID + ks * 32 + q * 8);
        bfrag a2 = *(const bfrag*)(h + (size_t)nA * HID + ks * 32 + q * 8);
#pragma unroll
        for (int nt = 0; nt < 4; nt++) {
            bfrag b1 = *(const bfrag*)(relT + (nt * 16 + l15) * HID + ks * 32 + q * 8);
            acc[nt] = __builtin_amdgcn_mfma_f32_16x16x32_bf16(a1, b1, acc[nt], 0, 0, 0);
            bfrag b2 = *(const bfrag*)(rootT + (nt * 16 + l15) * HID + ks * 32 + q * 8);
            acc[nt] = __builtin_amdgcn_mfma_f32_16x16x32_bf16(a2, b2, acc[nt], 0, 0, 0);
        }
    }
#pragma unroll
    for (int nt = 0; nt < 4; nt++) {
        float bs = bias[nt * 16 + l15];
#pragma unroll
        for (int r = 0; r < 4; r++)
            tpf[wv][(q * 4 + r) * 68 + nt * 16 + l15] = acc[nt][r] + bs;
    }
    __syncthreads();
#pragma unroll
    for (int i = 0; i < 4; i++) {
        int nr = node0 + i * 4 + q;
        if (nr < NN) {
            f4 v = *(const f4*)&tpf[wv][(i * 4 + q) * 68 + l15 * 4];
            *(f4*)(outn + (size_t)nr * OUTC + l15 * 4) = v;
        }
    }
}

// ---- global add pool (batch is sorted): 32 nodes per wave -----------------
__global__ __launch_bounds__(64) void k_pool(const float* __restrict__ outn,
                                             const int* __restrict__ batch,
                                             float* __restrict__ out) {
    int c = threadIdx.x;  // 0..63 channel
    int n0 = blockIdx.x * 32;
    int n1 = min(n0 + 32, NN);
    if (n0 >= NN) return;
    float acc = 0.f;
    int g = batch[n0];
#pragma unroll 4
    for (int n = n0; n < n1; n++) {
        int gn = batch[n];
        if (gn != g) {
            atomicAdd(&out[g * OUTC + c], acc);
            acc = 0.f; g = gn;
        }
        acc += outn[(size_t)n * OUTC + c];
    }
    atomicAdd(&out[g * OUTC + c], acc);
}

extern "C" void kernel_launch(void* const* d_in, const int* in_sizes, int n_in,
                              void* d_out, int out_size, void* d_ws, size_t ws_size,
                              hipStream_t stream) {
    const float* x      = (const float*)d_in[0];
    const int*   ei     = (const int*)d_in[1];
    const int*   batch  = (const int*)d_in[2];
    const float* lin_w  = (const float*)d_in[3];
    const float* lin_b  = (const float*)d_in[4];
    const float* rel_w  = (const float*)d_in[5];
    const float* root_w = (const float*)d_in[6];
    const float* conv_b = (const float*)d_in[7];
    const float* bn_g   = (const float*)d_in[8];
    const float* bn_b   = (const float*)d_in[9];
    const float* rel_l  = (const float*)d_in[10];
    const float* root_l = (const float*)d_in[11];
    const float* b_l    = (const float*)d_in[12];
    float* out = (float*)d_out;

    char* w = (char*)d_ws;
    ushort* h   = (ushort*)w; w += (size_t)NN * HID * 2;   // 12.8 MB bf16
    ushort* agg = (ushort*)w; w += (size_t)NN * HID * 2;   // 12.8 MB bf16
    ushort* h2  = (ushort*)w; w += (size_t)NN * HID * 2;   // 12.8 MB (also outn fp32)
    int* csr    = (int*)w;    w += (size_t)NE * 4;         // 3.2 MB
    int* deg    = (int*)w;    w += 200064;
    int* cursor = (int*)w;    w += 200064;
    int* offs   = (int*)w;    w += 200064;
    float* bnacc= (float*)w;  w += 4096;                   // 3 layers x 256 f32
    float* bn_sh= (float*)w;  w += 3 * 64 * 256 * 4;       // 192 KB shards
    int* bsum   = (int*)w;    w += 1024;
    ushort* wT  = (ushort*)w; w += 131072 * 2;
    float* outn = (float*)h2;

    hipMemsetAsync(deg, 0, NN * sizeof(int), stream);
    hipMemsetAsync(bn_sh, 0, 3 * 64 * 256 * sizeof(float), stream);
    hipMemsetAsync(out, 0, NG * OUTC * sizeof(float), stream);

    k_prep<<<512, 256, 0, stream>>>(lin_w, rel_w, root_w, rel_l, root_l, wT);
    k_hist<<<(NE + 255) / 256, 256, 0, stream>>>(ei, deg);
    k_bsum<<<NBLK, 256, 0, stream>>>(deg, bsum);
    k_scanb<<<1, 256, 0, stream>>>(bsum, offs);
    k_offs<<<NBLK, 256, 0, stream>>>(deg, bsum, offs, cursor);
    k_fill<<<(NE + 255) / 256, 256, 0, stream>>>(ei, cursor, csr);

    int gemm_blocks = (NN + 63) / 64;  // 782
    k_lin<<<gemm_blocks, 256, 0, stream>>>(x, wT, lin_b, h);

    for (int i = 0; i < NLAY; i++) {
        k_agg<<<(NN + 3) / 4, 256, 0, stream>>>(h, offs, csr, agg);
        k_conv<<<gemm_blocks, 256, 0, stream>>>(agg, h,
                                                wT + 16384 + i * 16384,
                                                wT + 65536 + i * 16384,
                                                conv_b + i * HID,
                                                bn_sh + i * 64 * 256, h2);
        k_bnred<<<1, 256, 0, stream>>>(bn_sh + i * 64 * 256, bnacc + i * 256);
        k_bnrelu<<<(NN * HID / 8 + 255) / 256, 256, 0, stream>>>(
            h2, bnacc + i * 256, bn_g + i * HID, bn_b + i * HID, h);
    }

    k_agg<<<(NN + 3) / 4, 256, 0, stream>>>(h, offs, csr, agg);
    k_final<<<gemm_blocks, 256, 0, stream>>>(agg, h, wT + 114688, wT + 122880, b_l, outn);
    k_pool<<<(NN + 31) / 32, 64, 0, stream>>>(outn, batch, out);
}

// Round 5
// 448.868 us; speedup vs baseline: 2.2274x; 1.1539x over previous
//
#include <hip/hip_runtime.h>

#define NN 50000
#define NE 800000
#define HID 128
#define OUTC 64
#define NG 128
#define NLAY 3
#define BN_EPS 1e-5f
#define NBKT 196          // ceil(NN/256) buckets of 256 nodes
#define NPB 256           // partition blocks
#define EPB ((NE + NPB - 1) / NPB)  // 3125 edges per partition block
#define LCAP 8192         // LDS csr segment capacity (bucket mean 4096, sd 64)

typedef __attribute__((ext_vector_type(8))) short bfrag;
typedef __attribute__((ext_vector_type(4))) float f4;

__device__ __forceinline__ ushort f2b(float f) {
    union { float f; unsigned u; } x; x.f = f;
    unsigned u = x.u;
    unsigned r = (u + 0x7fffu + ((u >> 16) & 1u)) >> 16;  // RNE
    return (ushort)r;
}
__device__ __forceinline__ float b2f(ushort b) {
    union { unsigned u; float f; } x; x.u = ((unsigned)b) << 16; return x.f;
}

// ---- weight prep: fp32 -> bf16, transposed to WT[n][k] --------------------
__global__ void k_prep(const float* __restrict__ lin_w, const float* __restrict__ rel_w,
                       const float* __restrict__ root_w, const float* __restrict__ rel_l,
                       const float* __restrict__ root_l, ushort* __restrict__ wT) {
    int idx = blockIdx.x * 256 + threadIdx.x;
    if (idx < 7 * 16384) {
        int m = idx >> 14, r = idx & 16383;
        int n = r >> 7, k = r & 127;
        const float* src = (m == 0) ? lin_w
                         : (m <= 3 ? rel_w + (m - 1) * 16384 : root_w + (m - 4) * 16384);
        wT[idx] = f2b(src[k * 128 + n]);
    } else if (idx < 7 * 16384 + 2 * 8192) {
        int r = idx - 7 * 16384;
        int m = r >> 13, rr = r & 8191;
        int n = rr >> 7, k = rr & 127;
        const float* src = m ? root_l : rel_l;
        wT[idx] = f2b(src[k * 64 + n]);
    }
}

// ---- CSR build via bucketed counting sort (no global per-edge atomics) ----
// phase 1: per-block LDS histogram of dst>>8
__global__ __launch_bounds__(256) void k_part1(const int* __restrict__ ei,
                                               int* __restrict__ p_hist) {
    __shared__ int hist[NBKT];
    int t = threadIdx.x;
    if (t < NBKT) hist[t] = 0;
    __syncthreads();
    int e0 = blockIdx.x * EPB, e1 = min(e0 + EPB, NE);
    for (int e = e0 + t; e < e1; e += 256)
        atomicAdd(&hist[ei[NE + e] >> 8], 1);           // LDS atomic
    __syncthreads();
    if (t < NBKT) p_hist[blockIdx.x * NBKT + t] = hist[t];
}

// phase 2: column-scan p_hist (exclusive over blocks per bucket) + bucket scan
__global__ void k_part2(int* __restrict__ p_hist, int* __restrict__ bstart,
                        int* __restrict__ offs) {
    __shared__ int tot[256];
    int t = threadIdx.x;
    int s = 0;
    if (t < NBKT) {
        for (int b = 0; b < NPB; b++) {
            int v = p_hist[b * NBKT + t];
            p_hist[b * NBKT + t] = s;
            s += v;
        }
    }
    tot[t] = (t < NBKT) ? s : 0;
    __syncthreads();
    for (int d = 1; d < 256; d <<= 1) {
        int u = 0;
        if (t >= d) u = tot[t - d];
        __syncthreads();
        tot[t] += u;
        __syncthreads();
    }
    if (t < NBKT) bstart[t] = tot[t] - s;   // exclusive bucket base
    if (t == 0) { bstart[NBKT] = NE; offs[NN] = NE; }
}

// phase 3: scatter edges into bucket-grouped order, packed (dst&255)<<16 | src
__global__ __launch_bounds__(256) void k_part3(const int* __restrict__ ei,
                                               const int* __restrict__ p_hist,
                                               const int* __restrict__ bstart,
                                               unsigned* __restrict__ epk) {
    __shared__ int cur[NBKT];
    int t = threadIdx.x;
    if (t < NBKT) cur[t] = p_hist[blockIdx.x * NBKT + t] + bstart[t];
    __syncthreads();
    int e0 = blockIdx.x * EPB, e1 = min(e0 + EPB, NE);
    for (int e = e0 + t; e < e1; e += 256) {
        int d = ei[NE + e], s = ei[e];
        int p = atomicAdd(&cur[d >> 8], 1);             // LDS atomic
        epk[p] = (unsigned)s | ((unsigned)(d & 255) << 16);
    }
}

// phase 4: per-bucket CSR segment built in LDS, fully coalesced global writes
__global__ __launch_bounds__(256) void k_csr(const unsigned* __restrict__ epk,
                                             const int* __restrict__ bstart,
                                             ushort* __restrict__ csr,
                                             int* __restrict__ offs) {
    __shared__ int cnt[256];
    __shared__ int cur[256];
    __shared__ ushort lcsr[LCAP];
    int b = blockIdx.x, t = threadIdx.x;
    int e0 = bstart[b], e1 = bstart[b + 1];
    int sz = e1 - e0;
    cnt[t] = 0;
    __syncthreads();
    for (int i = t; i < sz; i += 256)
        atomicAdd(&cnt[epk[e0 + i] >> 16], 1);
    __syncthreads();
    int v = cnt[t];
    for (int d = 1; d < 256; d <<= 1) {
        int u = 0;
        if (t >= d) u = cnt[t - d];
        __syncthreads();
        cnt[t] += u;
        __syncthreads();
    }
    int excl = cnt[t] - v;
    cur[t] = excl;
    int node = b * 256 + t;
    if (node < NN) offs[node] = e0 + excl;
    __syncthreads();
    for (int i = t; i < sz; i += 256) {
        unsigned pk = epk[e0 + i];
        int p = atomicAdd(&cur[pk >> 16], 1);           // LDS atomic
        lcsr[p] = (ushort)(pk & 0xffffu);
    }
    __syncthreads();
    for (int i = t; i < sz; i += 256) csr[e0 + i] = lcsr[i];
}

// ---- initial linear: h = bf16(x @ lin_w + lin_b) --------------------------
__global__ __launch_bounds__(256) void k_lin(const float* __restrict__ x,
                                             const ushort* __restrict__ wT,
                                             const float* __restrict__ bias,
                                             ushort* __restrict__ h) {
    __shared__ __align__(16) ushort tp[4][16 * 136];
    int t = threadIdx.x;
    int lane = t & 63, wv = t >> 6;
    int node0 = (blockIdx.x * 4 + wv) * 16;
    int l15 = lane & 15, q = lane >> 4;
    int nA = min(node0 + l15, NN - 1);
    f4 acc[8];
#pragma unroll
    for (int nt = 0; nt < 8; nt++) acc[nt] = (f4)0.0f;
#pragma unroll
    for (int ks = 0; ks < 4; ks++) {
        const float* ap = x + (size_t)nA * HID + ks * 32 + q * 8;
        bfrag a;
#pragma unroll
        for (int j = 0; j < 8; j++) a[j] = (short)f2b(ap[j]);
#pragma unroll
        for (int nt = 0; nt < 8; nt++) {
            bfrag b = *(const bfrag*)(wT + (nt * 16 + l15) * HID + ks * 32 + q * 8);
            acc[nt] = __builtin_amdgcn_mfma_f32_16x16x32_bf16(a, b, acc[nt], 0, 0, 0);
        }
    }
#pragma unroll
    for (int nt = 0; nt < 8; nt++) {
        float bs = bias[nt * 16 + l15];
#pragma unroll
        for (int r = 0; r < 4; r++)
            tp[wv][(q * 4 + r) * 136 + nt * 16 + l15] = f2b(acc[nt][r] + bs);
    }
    __syncthreads();
#pragma unroll
    for (int i = 0; i < 4; i++) {
        int nr = node0 + i * 4 + q;
        if (nr < NN) {
            bfrag tv = *(const bfrag*)&tp[wv][(i * 4 + q) * 136 + l15 * 8];
            *(bfrag*)(h + (size_t)nr * HID + l15 * 8) = tv;
        }
    }
}

// ---- aggregation: 4 edges per wave, 16B/lane ------------------------------
__global__ __launch_bounds__(256) void k_agg(const ushort* __restrict__ h,
                                             const int* __restrict__ offs,
                                             const ushort* __restrict__ csr,
                                             ushort* __restrict__ agg) {
    int gw = (blockIdx.x * 256 + threadIdx.x) >> 6;  // one wave per node
    int lane = threadIdx.x & 63;
    int slot = lane >> 4, c16 = lane & 15;
    if (gw >= NN) return;
    int e0 = offs[gw], e1 = offs[gw + 1];
    float a[8];
#pragma unroll
    for (int j = 0; j < 8; j++) a[j] = 0.f;
    int base = e0;
    for (; base + 8 <= e1; base += 8) {
        int s0 = csr[base + slot];
        int s1 = csr[base + 4 + slot];
        bfrag v0 = *(const bfrag*)(h + (size_t)s0 * HID + c16 * 8);
        bfrag v1 = *(const bfrag*)(h + (size_t)s1 * HID + c16 * 8);
#pragma unroll
        for (int j = 0; j < 8; j++)
            a[j] += b2f((ushort)v0[j]) + b2f((ushort)v1[j]);
    }
    if (base + 4 <= e1) {
        int s0 = csr[base + slot];
        bfrag v0 = *(const bfrag*)(h + (size_t)s0 * HID + c16 * 8);
#pragma unroll
        for (int j = 0; j < 8; j++) a[j] += b2f((ushort)v0[j]);
        base += 4;
    }
    int rem = e1 - base;
    if (slot < rem) {
        int s0 = csr[base + slot];
        bfrag v0 = *(const bfrag*)(h + (size_t)s0 * HID + c16 * 8);
#pragma unroll
        for (int j = 0; j < 8; j++) a[j] += b2f((ushort)v0[j]);
    }
#pragma unroll
    for (int j = 0; j < 8; j++) {
        a[j] += __shfl_xor(a[j], 16);
        a[j] += __shfl_xor(a[j], 32);
    }
    if (slot == 0) {
        bfrag o;
#pragma unroll
        for (int j = 0; j < 8; j++) o[j] = (short)f2b(a[j]);
        *(bfrag*)(agg + (size_t)gw * HID + c16 * 8) = o;
    }
}

// ---- conv layer: h2 = h + agg@rel + h@root + b; sharded BN partials -------
__global__ __launch_bounds__(256) void k_conv(const ushort* __restrict__ agg,
                                              const ushort* __restrict__ h,
                                              const ushort* __restrict__ relT,
                                              const ushort* __restrict__ rootT,
                                              const float* __restrict__ bias,
                                              float* __restrict__ bn_sh,
                                              ushort* __restrict__ h2) {
    __shared__ __align__(16) ushort tp[4][16 * 136];
    __shared__ float lsum[256];
    int t = threadIdx.x;
    lsum[t] = 0.f;
    int lane = t & 63, wv = t >> 6;
    int node0 = (blockIdx.x * 4 + wv) * 16;
    int l15 = lane & 15, q = lane >> 4;
    int nA = min(node0 + l15, NN - 1);
    bfrag hres[4];
    int nr[4];
#pragma unroll
    for (int i = 0; i < 4; i++) {
        nr[i] = node0 + i * 4 + q;
        int nc = min(nr[i], NN - 1);
        hres[i] = *(const bfrag*)(h + (size_t)nc * HID + l15 * 8);
    }
    f4 acc[8];
#pragma unroll
    for (int nt = 0; nt < 8; nt++) acc[nt] = (f4)0.0f;
#pragma unroll
    for (int ks = 0; ks < 4; ks++) {
        bfrag a1 = *(const bfrag*)(agg + (size_t)nA * HID + ks * 32 + q * 8);
        bfrag a2 = *(const bfrag*)(h + (size_t)nA * HID + ks * 32 + q * 8);
#pragma unroll
        for (int nt = 0; nt < 8; nt++) {
            bfrag b1 = *(const bfrag*)(relT + (nt * 16 + l15) * HID + ks * 32 + q * 8);
            acc[nt] = __builtin_amdgcn_mfma_f32_16x16x32_bf16(a1, b1, acc[nt], 0, 0, 0);
            bfrag b2 = *(const bfrag*)(rootT + (nt * 16 + l15) * HID + ks * 32 + q * 8);
            acc[nt] = __builtin_amdgcn_mfma_f32_16x16x32_bf16(a2, b2, acc[nt], 0, 0, 0);
        }
    }
#pragma unroll
    for (int nt = 0; nt < 8; nt++) {
        float bs = bias[nt * 16 + l15];
#pragma unroll
        for (int r = 0; r < 4; r++)
            tp[wv][(q * 4 + r) * 136 + nt * 16 + l15] = f2b(acc[nt][r] + bs);
    }
    __syncthreads();
    float s[8], s2[8];
#pragma unroll
    for (int j = 0; j < 8; j++) { s[j] = 0.f; s2[j] = 0.f; }
#pragma unroll
    for (int i = 0; i < 4; i++) {
        bfrag tv = *(const bfrag*)&tp[wv][(i * 4 + q) * 136 + l15 * 8];
        float m = (nr[i] < NN) ? 1.0f : 0.0f;
        bfrag o;
#pragma unroll
        for (int j = 0; j < 8; j++) {
            float v = b2f((ushort)tv[j]) + b2f((ushort)hres[i][j]);
            o[j] = (short)f2b(v);
            s[j] += m * v;
            s2[j] += m * v * v;
        }
        if (nr[i] < NN) *(bfrag*)(h2 + (size_t)nr[i] * HID + l15 * 8) = o;
    }
#pragma unroll
    for (int j = 0; j < 8; j++) {
        s[j] += __shfl_xor(s[j], 16);  s[j] += __shfl_xor(s[j], 32);
        s2[j] += __shfl_xor(s2[j], 16); s2[j] += __shfl_xor(s2[j], 32);
    }
    if (q == 0) {
#pragma unroll
        for (int j = 0; j < 8; j++) {
            atomicAdd(&lsum[l15 * 8 + j], s[j]);
            atomicAdd(&lsum[128 + l15 * 8 + j], s2[j]);
        }
    }
    __syncthreads();
    atomicAdd(&bn_sh[(blockIdx.x & 63) * 256 + t], lsum[t]);
}

// ---- reduce 64 shards -> bnacc[256] for one layer -------------------------
__global__ void k_bnred(const float* __restrict__ bn_sh, float* __restrict__ bnacc) {
    int t = threadIdx.x;  // 256
    float s = 0.f;
#pragma unroll 8
    for (int k = 0; k < 64; k++) s += bn_sh[k * 256 + t];
    bnacc[t] = s;
}

// ---- BN finalize + relu ---------------------------------------------------
__global__ void k_bnrelu(const ushort* __restrict__ h2, const float* __restrict__ bnacc,
                         const float* __restrict__ gamma, const float* __restrict__ beta,
                         ushort* __restrict__ h) {
    int t = blockIdx.x * 256 + threadIdx.x;
    if (t >= NN * HID / 8) return;
    int c0 = (t * 8) & 127;
    bfrag v = *(const bfrag*)(h2 + (size_t)t * 8);
    bfrag o;
#pragma unroll
    for (int j = 0; j < 8; j++) {
        int c = c0 + j;
        float mean = bnacc[c] * (1.0f / NN);
        float var = bnacc[HID + c] * (1.0f / NN) - mean * mean;
        float sc = gamma[c] * rsqrtf(var + BN_EPS);
        float sh = beta[c] - mean * sc;
        float x = b2f((ushort)v[j]) * sc + sh;
        o[j] = (short)f2b(fmaxf(x, 0.0f));
    }
    *(bfrag*)(h + (size_t)t * 8) = o;
}

// ---- final conv 128->64, fp32 node outputs --------------------------------
__global__ __launch_bounds__(256) void k_final(const ushort* __restrict__ agg,
                                               const ushort* __restrict__ h,
                                               const ushort* __restrict__ relT,
                                               const ushort* __restrict__ rootT,
                                               const float* __restrict__ bias,
                                               float* __restrict__ outn) {
    __shared__ __align__(16) float tpf[4][16 * 68];
    int t = threadIdx.x;
    int lane = t & 63, wv = t >> 6;
    int node0 = (blockIdx.x * 4 + wv) * 16;
    int l15 = lane & 15, q = lane >> 4;
    int nA = min(node0 + l15, NN - 1);
    f4 acc[4];
#pragma unroll
    for (int nt = 0; nt < 4; nt++) acc[nt] = (f4)0.0f;
#pragma unroll
    for (int ks = 0; ks < 4; ks++) {
        bfrag a1 = *(const bfrag*)(agg + (size_t)nA * HID + ks * 32 + q * 8);
        bfrag a2 = *(const bfrag*)(h + (size_t)nA * HID + ks * 32 + q * 8);
#pragma unroll
        for (int nt = 0; nt < 4; nt++) {
            bfrag b1 = *(const bfrag*)(relT + (nt * 16 + l15) * HID + ks * 32 + q * 8);
            acc[nt] = __builtin_amdgcn_mfma_f32_16x16x32_bf16(a1, b1, acc[nt], 0, 0, 0);
            bfrag b2 = *(const bfrag*)(rootT + (nt * 16 + l15) * HID + ks * 32 + q * 8);
            acc[nt] = __builtin_amdgcn_mfma_f32_16x16x32_bf16(a2, b2, acc[nt], 0, 0, 0);
        }
    }
#pragma unroll
    for (int nt = 0; nt < 4; nt++) {
        float bs = bias[nt * 16 + l15];
#pragma unroll
        for (int r = 0; r < 4; r++)
            tpf[wv][(q * 4 + r) * 68 + nt * 16 + l15] = acc[nt][r] + bs;
    }
    __syncthreads();
#pragma unroll
    for (int i = 0; i < 4; i++) {
        int nr = node0 + i * 4 + q;
        if (nr < NN) {
            f4 v = *(const f4*)&tpf[wv][(i * 4 + q) * 68 + l15 * 4];
            *(f4*)(outn + (size_t)nr * OUTC + l15 * 4) = v;
        }
    }
}

// ---- global add pool (batch is sorted): 32 nodes per wave -----------------
__global__ __launch_bounds__(64) void k_pool(const float* __restrict__ outn,
                                             const int* __restrict__ batch,
                                             float* __restrict__ out) {
    int c = threadIdx.x;  // 0..63 channel
    int n0 = blockIdx.x * 32;
    int n1 = min(n0 + 32, NN);
    if (n0 >= NN) return;
    float acc = 0.f;
    int g = batch[n0];
#pragma unroll 4
    for (int n = n0; n < n1; n++) {
        int gn = batch[n];
        if (gn != g) {
            atomicAdd(&out[g * OUTC + c], acc);
            acc = 0.f; g = gn;
        }
        acc += outn[(size_t)n * OUTC + c];
    }
    atomicAdd(&out[g * OUTC + c], acc);
}

extern "C" void kernel_launch(void* const* d_in, const int* in_sizes, int n_in,
                              void* d_out, int out_size, void* d_ws, size_t ws_size,
                              hipStream_t stream) {
    const float* x      = (const float*)d_in[0];
    const int*   ei     = (const int*)d_in[1];
    const int*   batch  = (const int*)d_in[2];
    const float* lin_w  = (const float*)d_in[3];
    const float* lin_b  = (const float*)d_in[4];
    const float* rel_w  = (const float*)d_in[5];
    const float* root_w = (const float*)d_in[6];
    const float* conv_b = (const float*)d_in[7];
    const float* bn_g   = (const float*)d_in[8];
    const float* bn_b   = (const float*)d_in[9];
    const float* rel_l  = (const float*)d_in[10];
    const float* root_l = (const float*)d_in[11];
    const float* b_l    = (const float*)d_in[12];
    float* out = (float*)d_out;

    char* w = (char*)d_ws;
    ushort* h    = (ushort*)w;   w += (size_t)NN * HID * 2;   // 12.8 MB bf16
    ushort* agg  = (ushort*)w;   w += (size_t)NN * HID * 2;   // 12.8 MB bf16
    ushort* h2   = (ushort*)w;   w += (size_t)NN * HID * 2;   // 12.8 MB (also outn fp32)
    unsigned* epk= (unsigned*)w; w += (size_t)NE * 4;         // 3.2 MB packed edges
    ushort* csr  = (ushort*)w;   w += (size_t)NE * 2;         // 1.6 MB
    int* p_hist  = (int*)w;      w += NPB * NBKT * 4;         // 200 KB
    int* bstart  = (int*)w;      w += 800;
    int* offs    = (int*)w;      w += 200064;
    float* bnacc = (float*)w;    w += 4096;                   // 3 layers x 256 f32
    float* bn_sh = (float*)w;    w += 3 * 64 * 256 * 4;       // 192 KB shards
    ushort* wT   = (ushort*)w;   w += 131072 * 2;
    float* outn  = (float*)h2;

    hipMemsetAsync(bn_sh, 0, 3 * 64 * 256 * sizeof(float), stream);
    hipMemsetAsync(out, 0, NG * OUTC * sizeof(float), stream);

    k_prep<<<512, 256, 0, stream>>>(lin_w, rel_w, root_w, rel_l, root_l, wT);
    k_part1<<<NPB, 256, 0, stream>>>(ei, p_hist);
    k_part2<<<1, 256, 0, stream>>>(p_hist, bstart, offs);
    k_part3<<<NPB, 256, 0, stream>>>(ei, p_hist, bstart, epk);
    k_csr<<<NBKT, 256, 0, stream>>>(epk, bstart, csr, offs);

    int gemm_blocks = (NN + 63) / 64;  // 782
    k_lin<<<gemm_blocks, 256, 0, stream>>>(x, wT, lin_b, h);

    for (int i = 0; i < NLAY; i++) {
        k_agg<<<(NN + 3) / 4, 256, 0, stream>>>(h, offs, csr, agg);
        k_conv<<<gemm_blocks, 256, 0, stream>>>(agg, h,
                                                wT + 16384 + i * 16384,
                                                wT + 65536 + i * 16384,
                                                conv_b + i * HID,
                                                bn_sh + i * 64 * 256, h2);
        k_bnred<<<1, 256, 0, stream>>>(bn_sh + i * 64 * 256, bnacc + i * 256);
        k_bnrelu<<<(NN * HID / 8 + 255) / 256, 256, 0, stream>>>(
            h2, bnacc + i * 256, bn_g + i * HID, bn_b + i * HID, h);
    }

    k_agg<<<(NN + 3) / 4, 256, 0, stream>>>(h, offs, csr, agg);
    k_final<<<gemm_blocks, 256, 0, stream>>>(agg, h, wT + 114688, wT + 122880, b_l, outn);
    k_pool<<<(NN + 31) / 32, 64, 0, stream>>>(outn, batch, out);
}

// Round 6
// 426.316 us; speedup vs baseline: 2.3452x; 1.0529x over previous
//
#include <hip/hip_runtime.h>

#define NN 50000
#define NE 800000
#define HID 128
#define OUTC 64
#define NG 128
#define NLAY 3
#define BN_EPS 1e-5f
#define NBKT 196          // ceil(NN/256) buckets of 256 nodes
#define NPB 256           // partition blocks
#define EPB ((NE + NPB - 1) / NPB)
#define LCAP 8192

typedef __attribute__((ext_vector_type(8))) short bfrag;
typedef __attribute__((ext_vector_type(4))) float f4;

__device__ __forceinline__ ushort f2b(float f) {
    union { float f; unsigned u; } x; x.f = f;
    unsigned u = x.u;
    unsigned r = (u + 0x7fffu + ((u >> 16) & 1u)) >> 16;  // RNE
    return (ushort)r;
}
__device__ __forceinline__ float b2f(ushort b) {
    union { unsigned u; float f; } x; x.u = ((unsigned)b) << 16; return x.f;
}

// ---- weight prep + buffer init -------------------------------------------
__global__ void k_prep(const float* __restrict__ lin_w, const float* __restrict__ rel_w,
                       const float* __restrict__ root_w, const float* __restrict__ rel_l,
                       const float* __restrict__ root_l, ushort* __restrict__ wT,
                       float* __restrict__ aff, float* __restrict__ bn_sh,
                       float* __restrict__ out) {
    int idx = blockIdx.x * 256 + threadIdx.x;
    if (idx < 7 * 16384) {
        int m = idx >> 14, r = idx & 16383;
        int n = r >> 7, k = r & 127;
        const float* src = (m == 0) ? lin_w
                         : (m <= 3 ? rel_w + (m - 1) * 16384 : root_w + (m - 4) * 16384);
        wT[idx] = f2b(src[k * 128 + n]);
    } else {
        int r = idx - 7 * 16384;
        int m = r >> 13, rr = r & 8191;
        int n = rr >> 7, k = rr & 127;
        const float* src = m ? root_l : rel_l;
        wT[idx] = f2b(src[k * 64 + n]);
    }
    if (idx < 128) aff[idx] = 1.0f;                 // layer-0 identity scale
    else if (idx < 256) aff[idx] = 0.0f;            // layer-0 zero shift
    if (idx < NG * OUTC) out[idx] = 0.0f;
    if (idx < NLAY * 64 * 256) bn_sh[idx] = 0.0f;
}

// ---- CSR build via bucketed counting sort (LDS atomics only) --------------
__global__ __launch_bounds__(256) void k_part1(const int* __restrict__ ei,
                                               int* __restrict__ p_hist) {
    __shared__ int hist[NBKT];
    int t = threadIdx.x;
    if (t < NBKT) hist[t] = 0;
    __syncthreads();
    int e0 = blockIdx.x * EPB, e1 = min(e0 + EPB, NE);
    for (int e = e0 + t; e < e1; e += 256)
        atomicAdd(&hist[ei[NE + e] >> 8], 1);
    __syncthreads();
    if (t < NBKT) p_hist[blockIdx.x * NBKT + t] = hist[t];
}

__global__ void k_part2(int* __restrict__ p_hist, int* __restrict__ bstart,
                        int* __restrict__ offs) {
    __shared__ int tot[256];
    int t = threadIdx.x;
    int s = 0;
    if (t < NBKT) {
        for (int b = 0; b < NPB; b++) {
            int v = p_hist[b * NBKT + t];
            p_hist[b * NBKT + t] = s;
            s += v;
        }
    }
    tot[t] = (t < NBKT) ? s : 0;
    __syncthreads();
    for (int d = 1; d < 256; d <<= 1) {
        int u = 0;
        if (t >= d) u = tot[t - d];
        __syncthreads();
        tot[t] += u;
        __syncthreads();
    }
    if (t < NBKT) bstart[t] = tot[t] - s;
    if (t == 0) { bstart[NBKT] = NE; offs[NN] = NE; }
}

__global__ __launch_bounds__(256) void k_part3(const int* __restrict__ ei,
                                               const int* __restrict__ p_hist,
                                               const int* __restrict__ bstart,
                                               unsigned* __restrict__ epk) {
    __shared__ int cur[NBKT];
    int t = threadIdx.x;
    if (t < NBKT) cur[t] = p_hist[blockIdx.x * NBKT + t] + bstart[t];
    __syncthreads();
    int e0 = blockIdx.x * EPB, e1 = min(e0 + EPB, NE);
    for (int e = e0 + t; e < e1; e += 256) {
        int d = ei[NE + e], s = ei[e];
        int p = atomicAdd(&cur[d >> 8], 1);
        epk[p] = (unsigned)s | ((unsigned)(d & 255) << 16);
    }
}

__global__ __launch_bounds__(256) void k_csr(const unsigned* __restrict__ epk,
                                             const int* __restrict__ bstart,
                                             ushort* __restrict__ csr,
                                             int* __restrict__ offs) {
    __shared__ int cnt[256];
    __shared__ int cur[256];
    __shared__ ushort lcsr[LCAP];
    int b = blockIdx.x, t = threadIdx.x;
    int e0 = bstart[b], e1 = bstart[b + 1];
    int sz = e1 - e0;
    cnt[t] = 0;
    __syncthreads();
    for (int i = t; i < sz; i += 256)
        atomicAdd(&cnt[epk[e0 + i] >> 16], 1);
    __syncthreads();
    int v = cnt[t];
    for (int d = 1; d < 256; d <<= 1) {
        int u = 0;
        if (t >= d) u = cnt[t - d];
        __syncthreads();
        cnt[t] += u;
        __syncthreads();
    }
    int excl = cnt[t] - v;
    cur[t] = excl;
    int node = b * 256 + t;
    if (node < NN) offs[node] = e0 + excl;
    __syncthreads();
    for (int i = t; i < sz; i += 256) {
        unsigned pk = epk[e0 + i];
        int p = atomicAdd(&cur[pk >> 16], 1);
        lcsr[p] = (ushort)(pk & 0xffffu);
    }
    __syncthreads();
    for (int i = t; i < sz; i += 256) csr[e0 + i] = lcsr[i];
}

// ---- initial linear: h = bf16(x @ lin_w + lin_b) --------------------------
__global__ __launch_bounds__(256) void k_lin(const float* __restrict__ x,
                                             const ushort* __restrict__ wT,
                                             const float* __restrict__ bias,
                                             ushort* __restrict__ h) {
    __shared__ __align__(16) ushort tp[4][16 * 136];
    int t = threadIdx.x;
    int lane = t & 63, wv = t >> 6;
    int node0 = (blockIdx.x * 4 + wv) * 16;
    int l15 = lane & 15, q = lane >> 4;
    int nA = min(node0 + l15, NN - 1);
    f4 acc[8];
#pragma unroll
    for (int nt = 0; nt < 8; nt++) acc[nt] = (f4)0.0f;
#pragma unroll
    for (int ks = 0; ks < 4; ks++) {
        const float* ap = x + (size_t)nA * HID + ks * 32 + q * 8;
        f4 x0 = *(const f4*)ap;
        f4 x1 = *(const f4*)(ap + 4);
        bfrag a;
#pragma unroll
        for (int j = 0; j < 4; j++) { a[j] = (short)f2b(x0[j]); a[4 + j] = (short)f2b(x1[j]); }
#pragma unroll
        for (int nt = 0; nt < 8; nt++) {
            bfrag b = *(const bfrag*)(wT + (nt * 16 + l15) * HID + ks * 32 + q * 8);
            acc[nt] = __builtin_amdgcn_mfma_f32_16x16x32_bf16(a, b, acc[nt], 0, 0, 0);
        }
    }
#pragma unroll
    for (int nt = 0; nt < 8; nt++) {
        float bs = bias[nt * 16 + l15];
#pragma unroll
        for (int r = 0; r < 4; r++)
            tp[wv][(q * 4 + r) * 136 + nt * 16 + l15] = f2b(acc[nt][r] + bs);
    }
    __syncthreads();
#pragma unroll
    for (int i = 0; i < 4; i++) {
        int nr = node0 + i * 4 + q;
        if (nr < NN) {
            bfrag tv = *(const bfrag*)&tp[wv][(i * 4 + q) * 136 + l15 * 8];
            *(bfrag*)(h + (size_t)nr * HID + l15 * 8) = tv;
        }
    }
}

// ---- aggregation with fused BN+relu of source rows ------------------------
// agg[n] = sum_e relu_negk(hb[src[e]] * sc + sh)
__global__ __launch_bounds__(256) void k_agg(const ushort* __restrict__ hb,
                                             const int* __restrict__ offs,
                                             const ushort* __restrict__ csr,
                                             const float* __restrict__ aff,
                                             float negk,
                                             ushort* __restrict__ agg) {
    int gw = (blockIdx.x * 256 + threadIdx.x) >> 6;  // one wave per node
    int lane = threadIdx.x & 63;
    int slot = lane >> 4, c16 = lane & 15;
    if (gw >= NN) return;
    float scv[8], shv[8];
    *(f4*)&scv[0] = *(const f4*)(aff + c16 * 8);
    *(f4*)&scv[4] = *(const f4*)(aff + c16 * 8 + 4);
    *(f4*)&shv[0] = *(const f4*)(aff + 128 + c16 * 8);
    *(f4*)&shv[4] = *(const f4*)(aff + 128 + c16 * 8 + 4);
    int e0 = offs[gw], e1 = offs[gw + 1];
    float a[8];
#pragma unroll
    for (int j = 0; j < 8; j++) a[j] = 0.f;
    int base = e0;
    for (; base + 8 <= e1; base += 8) {
        int s0 = csr[base + slot];
        int s1 = csr[base + 4 + slot];
        bfrag v0 = *(const bfrag*)(hb + (size_t)s0 * HID + c16 * 8);
        bfrag v1 = *(const bfrag*)(hb + (size_t)s1 * HID + c16 * 8);
#pragma unroll
        for (int j = 0; j < 8; j++) {
            float t0 = b2f((ushort)v0[j]) * scv[j] + shv[j];
            float t1 = b2f((ushort)v1[j]) * scv[j] + shv[j];
            a[j] += fmaxf(t0, t0 * negk) + fmaxf(t1, t1 * negk);
        }
    }
    if (base + 4 <= e1) {
        int s0 = csr[base + slot];
        bfrag v0 = *(const bfrag*)(hb + (size_t)s0 * HID + c16 * 8);
#pragma unroll
        for (int j = 0; j < 8; j++) {
            float t0 = b2f((ushort)v0[j]) * scv[j] + shv[j];
            a[j] += fmaxf(t0, t0 * negk);
        }
        base += 4;
    }
    int rem = e1 - base;
    if (slot < rem) {
        int s0 = csr[base + slot];
        bfrag v0 = *(const bfrag*)(hb + (size_t)s0 * HID + c16 * 8);
#pragma unroll
        for (int j = 0; j < 8; j++) {
            float t0 = b2f((ushort)v0[j]) * scv[j] + shv[j];
            a[j] += fmaxf(t0, t0 * negk);
        }
    }
#pragma unroll
    for (int j = 0; j < 8; j++) {
        a[j] += __shfl_xor(a[j], 16);
        a[j] += __shfl_xor(a[j], 32);
    }
    if (slot == 0) {
        bfrag o;
#pragma unroll
        for (int j = 0; j < 8; j++) o[j] = (short)f2b(a[j]);
        *(bfrag*)(agg + (size_t)gw * HID + c16 * 8) = o;
    }
}

// ---- conv layer with fused input BN+relu; writes pre-BN h2; BN partials ---
__global__ __launch_bounds__(256) void k_conv(const ushort* __restrict__ agg,
                                              const ushort* __restrict__ hb,
                                              const ushort* __restrict__ relT,
                                              const ushort* __restrict__ rootT,
                                              const float* __restrict__ bias,
                                              const float* __restrict__ aff,
                                              float negk,
                                              float* __restrict__ bn_sh,
                                              ushort* __restrict__ h2) {
    __shared__ __align__(16) ushort tp[4][16 * 136];
    __shared__ float lsum[256];
    __shared__ float lsc[128], lsh[128];
    int t = threadIdx.x;
    lsum[t] = 0.f;
    if (t < 128) { lsc[t] = aff[t]; lsh[t] = aff[128 + t]; }
    int lane = t & 63, wv = t >> 6;
    int node0 = (blockIdx.x * 4 + wv) * 16;
    int l15 = lane & 15, q = lane >> 4;
    int nA = min(node0 + l15, NN - 1);
    bfrag hres[4];
    int nr[4];
#pragma unroll
    for (int i = 0; i < 4; i++) {
        nr[i] = node0 + i * 4 + q;
        int nc = min(nr[i], NN - 1);
        hres[i] = *(const bfrag*)(hb + (size_t)nc * HID + l15 * 8);
    }
    __syncthreads();  // lsc/lsh visible
    f4 acc[8];
#pragma unroll
    for (int nt = 0; nt < 8; nt++) acc[nt] = (f4)0.0f;
#pragma unroll
    for (int ks = 0; ks < 4; ks++) {
        bfrag a1 = *(const bfrag*)(agg + (size_t)nA * HID + ks * 32 + q * 8);
        bfrag a2r = *(const bfrag*)(hb + (size_t)nA * HID + ks * 32 + q * 8);
        float asc[8], ash[8];
        *(f4*)&asc[0] = *(const f4*)&lsc[ks * 32 + q * 8];
        *(f4*)&asc[4] = *(const f4*)&lsc[ks * 32 + q * 8 + 4];
        *(f4*)&ash[0] = *(const f4*)&lsh[ks * 32 + q * 8];
        *(f4*)&ash[4] = *(const f4*)&lsh[ks * 32 + q * 8 + 4];
        bfrag a2;
#pragma unroll
        for (int j = 0; j < 8; j++) {
            float tt = b2f((ushort)a2r[j]) * asc[j] + ash[j];
            a2[j] = (short)f2b(fmaxf(tt, tt * negk));
        }
#pragma unroll
        for (int nt = 0; nt < 8; nt++) {
            bfrag b1 = *(const bfrag*)(relT + (nt * 16 + l15) * HID + ks * 32 + q * 8);
            acc[nt] = __builtin_amdgcn_mfma_f32_16x16x32_bf16(a1, b1, acc[nt], 0, 0, 0);
            bfrag b2 = *(const bfrag*)(rootT + (nt * 16 + l15) * HID + ks * 32 + q * 8);
            acc[nt] = __builtin_amdgcn_mfma_f32_16x16x32_bf16(a2, b2, acc[nt], 0, 0, 0);
        }
    }
#pragma unroll
    for (int nt = 0; nt < 8; nt++) {
        float bs = bias[nt * 16 + l15];
#pragma unroll
        for (int r = 0; r < 4; r++)
            tp[wv][(q * 4 + r) * 136 + nt * 16 + l15] = f2b(acc[nt][r] + bs);
    }
    __syncthreads();
    float rsc[8], rsh[8];
    *(f4*)&rsc[0] = *(const f4*)&lsc[l15 * 8];
    *(f4*)&rsc[4] = *(const f4*)&lsc[l15 * 8 + 4];
    *(f4*)&rsh[0] = *(const f4*)&lsh[l15 * 8];
    *(f4*)&rsh[4] = *(const f4*)&lsh[l15 * 8 + 4];
    float s[8], s2[8];
#pragma unroll
    for (int j = 0; j < 8; j++) { s[j] = 0.f; s2[j] = 0.f; }
#pragma unroll
    for (int i = 0; i < 4; i++) {
        bfrag tv = *(const bfrag*)&tp[wv][(i * 4 + q) * 136 + l15 * 8];
        float m = (nr[i] < NN) ? 1.0f : 0.0f;
        bfrag o;
#pragma unroll
        for (int j = 0; j < 8; j++) {
            float tt = b2f((ushort)hres[i][j]) * rsc[j] + rsh[j];
            float res = fmaxf(tt, tt * negk);
            float v = b2f((ushort)tv[j]) + res;
            o[j] = (short)f2b(v);
            s[j] += m * v;
            s2[j] += m * v * v;
        }
        if (nr[i] < NN) *(bfrag*)(h2 + (size_t)nr[i] * HID + l15 * 8) = o;
    }
#pragma unroll
    for (int j = 0; j < 8; j++) {
        s[j] += __shfl_xor(s[j], 16);  s[j] += __shfl_xor(s[j], 32);
        s2[j] += __shfl_xor(s2[j], 16); s2[j] += __shfl_xor(s2[j], 32);
    }
    if (q == 0) {
#pragma unroll
        for (int j = 0; j < 8; j++) {
            atomicAdd(&lsum[l15 * 8 + j], s[j]);
            atomicAdd(&lsum[128 + l15 * 8 + j], s2[j]);
        }
    }
    __syncthreads();
    atomicAdd(&bn_sh[(blockIdx.x & 63) * 256 + t], lsum[t]);
}

// ---- reduce shards + compute next-layer affine (sc, sh) -------------------
__global__ void k_bnfin(const float* __restrict__ bn_sh, const float* __restrict__ gamma,
                        const float* __restrict__ beta, float* __restrict__ aff_out) {
    int t = threadIdx.x;  // 128
    float s = 0.f, s2 = 0.f;
#pragma unroll 8
    for (int k = 0; k < 64; k++) {
        s += bn_sh[k * 256 + t];
        s2 += bn_sh[k * 256 + 128 + t];
    }
    float mean = s * (1.0f / NN);
    float var = s2 * (1.0f / NN) - mean * mean;
    float sc = gamma[t] * rsqrtf(var + BN_EPS);
    aff_out[t] = sc;
    aff_out[128 + t] = beta[t] - mean * sc;
}

// ---- final conv 128->64 with fused input BN+relu and fused add-pool -------
__global__ __launch_bounds__(256) void k_final(const ushort* __restrict__ agg,
                                               const ushort* __restrict__ hb,
                                               const ushort* __restrict__ relT,
                                               const ushort* __restrict__ rootT,
                                               const float* __restrict__ bias,
                                               const float* __restrict__ aff,
                                               const int* __restrict__ batch,
                                               float* __restrict__ out) {
    __shared__ __align__(16) float tpf[4][16 * 68];
    __shared__ float lsc[128], lsh[128];
    __shared__ int bt[64];
    int t = threadIdx.x;
    if (t < 128) { lsc[t] = aff[t]; lsh[t] = aff[128 + t]; }
    if (t < 64) {
        int n = blockIdx.x * 64 + t;
        bt[t] = (n < NN) ? batch[n] : -1;
    }
    int lane = t & 63, wv = t >> 6;
    int node0 = (blockIdx.x * 4 + wv) * 16;
    int l15 = lane & 15, q = lane >> 4;
    int nA = min(node0 + l15, NN - 1);
    __syncthreads();
    f4 acc[4];
#pragma unroll
    for (int nt = 0; nt < 4; nt++) acc[nt] = (f4)0.0f;
#pragma unroll
    for (int ks = 0; ks < 4; ks++) {
        bfrag a1 = *(const bfrag*)(agg + (size_t)nA * HID + ks * 32 + q * 8);
        bfrag a2r = *(const bfrag*)(hb + (size_t)nA * HID + ks * 32 + q * 8);
        float asc[8], ash[8];
        *(f4*)&asc[0] = *(const f4*)&lsc[ks * 32 + q * 8];
        *(f4*)&asc[4] = *(const f4*)&lsc[ks * 32 + q * 8 + 4];
        *(f4*)&ash[0] = *(const f4*)&lsh[ks * 32 + q * 8];
        *(f4*)&ash[4] = *(const f4*)&lsh[ks * 32 + q * 8 + 4];
        bfrag a2;
#pragma unroll
        for (int j = 0; j < 8; j++) {
            float tt = b2f((ushort)a2r[j]) * asc[j] + ash[j];
            a2[j] = (short)f2b(fmaxf(tt, 0.0f));
        }
#pragma unroll
        for (int nt = 0; nt < 4; nt++) {
            bfrag b1 = *(const bfrag*)(relT + (nt * 16 + l15) * HID + ks * 32 + q * 8);
            acc[nt] = __builtin_amdgcn_mfma_f32_16x16x32_bf16(a1, b1, acc[nt], 0, 0, 0);
            bfrag b2 = *(const bfrag*)(rootT + (nt * 16 + l15) * HID + ks * 32 + q * 8);
            acc[nt] = __builtin_amdgcn_mfma_f32_16x16x32_bf16(a2, b2, acc[nt], 0, 0, 0);
        }
    }
#pragma unroll
    for (int nt = 0; nt < 4; nt++) {
        float bs = bias[nt * 16 + l15];
#pragma unroll
        for (int r = 0; r < 4; r++)
            tpf[wv][(q * 4 + r) * 68 + nt * 16 + l15] = acc[nt][r] + bs;
    }
    __syncthreads();
    // fused global_add_pool: batch is sorted; run-segmented per 16-node group
    int c = t & 63, grp = t >> 6;
    int g = bt[grp * 16];
    if (g >= 0) {
        float pacc = 0.f;
#pragma unroll
        for (int r = 0; r < 16; r++) {
            int b = bt[grp * 16 + r];
            if (b < 0) break;
            float v = tpf[grp][r * 68 + c];
            if (b != g) { atomicAdd(&out[g * OUTC + c], pacc); pacc = 0.f; g = b; }
            pacc += v;
        }
        atomicAdd(&out[g * OUTC + c], pacc);
    }
}

extern "C" void kernel_launch(void* const* d_in, const int* in_sizes, int n_in,
                              void* d_out, int out_size, void* d_ws, size_t ws_size,
                              hipStream_t stream) {
    const float* x      = (const float*)d_in[0];
    const int*   ei     = (const int*)d_in[1];
    const int*   batch  = (const int*)d_in[2];
    const float* lin_w  = (const float*)d_in[3];
    const float* lin_b  = (const float*)d_in[4];
    const float* rel_w  = (const float*)d_in[5];
    const float* root_w = (const float*)d_in[6];
    const float* conv_b = (const float*)d_in[7];
    const float* bn_g   = (const float*)d_in[8];
    const float* bn_b   = (const float*)d_in[9];
    const float* rel_l  = (const float*)d_in[10];
    const float* root_l = (const float*)d_in[11];
    const float* b_l    = (const float*)d_in[12];
    float* out = (float*)d_out;

    char* w = (char*)d_ws;
    ushort* h    = (ushort*)w;   w += (size_t)NN * HID * 2;   // 12.8 MB bf16
    ushort* h2   = (ushort*)w;   w += (size_t)NN * HID * 2;   // 12.8 MB bf16
    ushort* agg  = (ushort*)w;   w += (size_t)NN * HID * 2;   // 12.8 MB bf16
    unsigned* epk= (unsigned*)w; w += (size_t)NE * 4;         // 3.2 MB
    ushort* csr  = (ushort*)w;   w += (size_t)NE * 2;         // 1.6 MB
    int* p_hist  = (int*)w;      w += NPB * NBKT * 4;
    int* bstart  = (int*)w;      w += 800;
    int* offs    = (int*)w;      w += 200064;
    float* aff   = (float*)w;    w += 4 * 256 * 4;            // per-layer (sc,sh)
    float* bn_sh = (float*)w;    w += NLAY * 64 * 256 * 4;    // 192 KB shards
    ushort* wT   = (ushort*)w;   w += 131072 * 2;

    k_prep<<<512, 256, 0, stream>>>(lin_w, rel_w, root_w, rel_l, root_l, wT,
                                    aff, bn_sh, out);
    k_part1<<<NPB, 256, 0, stream>>>(ei, p_hist);
    k_part2<<<1, 256, 0, stream>>>(p_hist, bstart, offs);
    k_part3<<<NPB, 256, 0, stream>>>(ei, p_hist, bstart, epk);
    k_csr<<<NBKT, 256, 0, stream>>>(epk, bstart, csr, offs);

    int gemm_blocks = (NN + 63) / 64;  // 782
    k_lin<<<gemm_blocks, 256, 0, stream>>>(x, wT, lin_b, h);

    ushort* hb = h;
    ushort* ho = h2;
    for (int i = 0; i < NLAY; i++) {
        float negk = (i == 0) ? 1.0f : 0.0f;
        k_agg<<<(NN + 3) / 4, 256, 0, stream>>>(hb, offs, csr, aff + i * 256, negk, agg);
        k_conv<<<gemm_blocks, 256, 0, stream>>>(agg, hb,
                                                wT + 16384 + i * 16384,
                                                wT + 65536 + i * 16384,
                                                conv_b + i * HID,
                                                aff + i * 256, negk,
                                                bn_sh + i * 64 * 256, ho);
        k_bnfin<<<1, 128, 0, stream>>>(bn_sh + i * 64 * 256, bn_g + i * HID,
                                       bn_b + i * HID, aff + (i + 1) * 256);
        ushort* tmp = hb; hb = ho; ho = tmp;
    }

    k_agg<<<(NN + 3) / 4, 256, 0, stream>>>(hb, offs, csr, aff + 3 * 256, 0.0f, agg);
    k_final<<<gemm_blocks, 256, 0, stream>>>(agg, hb, wT + 114688, wT + 122880, b_l,
                                             aff + 3 * 256, batch, out);
}